// Round 1
// baseline (816.960 us; speedup 1.0000x reference)
//
#include <hip/hip_runtime.h>
#include <math.h>

#define N_NODES 20000
#define N_EDGES 320000
#define ETOT    (N_EDGES + N_NODES)
#define NGRAPH  64
#define DIN     256
#define DD      128
#define NH      4
#define NL      3
#define HPD     (NH*DD)   // 512
#define EPS_BN  1e-5f
#define SLOPE   0.2f

__device__ __forceinline__ float lrelu(float x) { return x >= 0.f ? x : SLOPE * x; }

// ---------------- CSR build ----------------
__global__ void hist_kernel(const int* __restrict__ ei, int* __restrict__ hist) {
  int idx = blockIdx.x * 256 + threadIdx.x;
  if (idx >= ETOT) return;
  int d = (idx < N_EDGES) ? ei[N_EDGES + idx] : (idx - N_EDGES);
  atomicAdd(&hist[d], 1);
}

__global__ __launch_bounds__(1024) void scan_kernel(const int* __restrict__ hist,
                                                    int* __restrict__ offs,
                                                    int* __restrict__ cursor) {
  __shared__ int sh[1024];
  int tid = threadIdx.x;
  int carry = 0;
  for (int base = 0; base < N_NODES; base += 1024) {
    int i = base + tid;
    int x = (i < N_NODES) ? hist[i] : 0;
    __syncthreads();
    sh[tid] = x;
    __syncthreads();
    #pragma unroll
    for (int d = 1; d < 1024; d <<= 1) {
      int v = (tid >= d) ? sh[tid - d] : 0;
      __syncthreads();
      sh[tid] += v;
      __syncthreads();
    }
    int incl = sh[tid];
    if (i < N_NODES) { int e = carry + incl - x; offs[i] = e; cursor[i] = e; }
    carry += sh[1023];
  }
  if (tid == 0) offs[N_NODES] = carry;
}

__global__ void scatter_kernel(const int* __restrict__ ei, int* __restrict__ cursor,
                               int* __restrict__ esrc) {
  int idx = blockIdx.x * 256 + threadIdx.x;
  if (idx >= ETOT) return;
  int s, d;
  if (idx < N_EDGES) { s = ei[idx]; d = ei[N_EDGES + idx]; }
  else { s = idx - N_EDGES; d = s; }
  int pos = atomicAdd(&cursor[d], 1);
  esrc[pos] = s;
}

// ---------------- GEMM NT: C[M,Nc] = act(A[M,K] @ B[Nc,K]^T + bias) ----------------
#define BM 64
#define BN 64
#define BKK 128

__global__ __launch_bounds__(256) void gemm_nt(const float* __restrict__ A,
    const float* __restrict__ B, float* __restrict__ C, int M, int Nc, int K,
    const float* __restrict__ bias, int do_relu)
{
  __shared__ float As[BM][BKK];
  __shared__ float Bs[BN][BKK];
  int tid = threadIdx.x;
  int m0 = blockIdx.y * BM, n0 = blockIdx.x * BN;
  int ty = tid >> 4, tx = tid & 15;
  float acc[4][4];
  #pragma unroll
  for (int i = 0; i < 4; ++i)
    #pragma unroll
    for (int j = 0; j < 4; ++j) acc[i][j] = 0.f;

  const int swA = ty & 7;   // read-side swizzle (row>>2 == ty for rows ty*4+i, i<4)
  const int swB = tx & 7;

  for (int kc = 0; kc < K; kc += BKK) {
    __syncthreads();
    #pragma unroll
    for (int i = 0; i < 8; ++i) {
      int f4 = tid + i * 256;
      int row = f4 >> 5, c4 = f4 & 31;
      int sw = c4 ^ ((row >> 2) & 7);
      int gr = m0 + row;
      float4 va = make_float4(0.f, 0.f, 0.f, 0.f);
      if (gr < M) va = *(const float4*)&A[(size_t)gr * K + kc + c4 * 4];
      *(float4*)&As[row][sw * 4] = va;
      int gb = n0 + row;
      float4 vb = *(const float4*)&B[(size_t)gb * K + kc + c4 * 4];
      *(float4*)&Bs[row][sw * 4] = vb;
    }
    __syncthreads();
    #pragma unroll 8
    for (int k4 = 0; k4 < BKK / 4; ++k4) {
      float4 av[4], bv[4];
      int ca = (k4 ^ swA) * 4;
      int cb = (k4 ^ swB) * 4;
      #pragma unroll
      for (int i = 0; i < 4; ++i) av[i] = *(const float4*)&As[ty * 4 + i][ca];
      #pragma unroll
      for (int j = 0; j < 4; ++j) bv[j] = *(const float4*)&Bs[tx * 4 + j][cb];
      #pragma unroll
      for (int i = 0; i < 4; ++i)
        #pragma unroll
        for (int j = 0; j < 4; ++j) {
          acc[i][j] = fmaf(av[i].x, bv[j].x, acc[i][j]);
          acc[i][j] = fmaf(av[i].y, bv[j].y, acc[i][j]);
          acc[i][j] = fmaf(av[i].z, bv[j].z, acc[i][j]);
          acc[i][j] = fmaf(av[i].w, bv[j].w, acc[i][j]);
        }
    }
  }
  // epilogue
  int ncol = n0 + tx * 4;
  float4 bz = make_float4(0.f, 0.f, 0.f, 0.f);
  if (bias) bz = *(const float4*)&bias[ncol];
  #pragma unroll
  for (int i = 0; i < 4; ++i) {
    int gr = m0 + ty * 4 + i;
    if (gr < M) {
      float4 o;
      o.x = acc[i][0] + bz.x; o.y = acc[i][1] + bz.y;
      o.z = acc[i][2] + bz.z; o.w = acc[i][3] + bz.w;
      if (do_relu) {
        o.x = fmaxf(o.x, 0.f); o.y = fmaxf(o.y, 0.f);
        o.z = fmaxf(o.z, 0.f); o.w = fmaxf(o.w, 0.f);
      }
      *(float4*)&C[(size_t)gr * Nc + ncol] = o;
    }
  }
}

// ---------------- attention dot products: a_src/a_dst [N,4] ----------------
__global__ __launch_bounds__(256) void attn_dots(const float* __restrict__ HP,
    const float* __restrict__ atts, const float* __restrict__ attd,
    float* __restrict__ a_s, float* __restrict__ a_d)
{
  int lane = threadIdx.x & 63;
  int n = blockIdx.x * 4 + (threadIdx.x >> 6);
  const float4* hp = (const float4*)&HP[(size_t)n * HPD + lane * 8];
  float4 p0 = hp[0], p1 = hp[1];
  const float4* wsv = (const float4*)&atts[lane * 8];
  float4 s0 = wsv[0], s1 = wsv[1];
  const float4* wdv = (const float4*)&attd[lane * 8];
  float4 d0 = wdv[0], d1 = wdv[1];
  float ps = p0.x*s0.x + p0.y*s0.y + p0.z*s0.z + p0.w*s0.w
           + p1.x*s1.x + p1.y*s1.y + p1.z*s1.z + p1.w*s1.w;
  float pd = p0.x*d0.x + p0.y*d0.y + p0.z*d0.z + p0.w*d0.w
           + p1.x*d1.x + p1.y*d1.y + p1.z*d1.z + p1.w*d1.w;
  #pragma unroll
  for (int m = 1; m <= 8; m <<= 1) {
    ps += __shfl_xor(ps, m);
    pd += __shfl_xor(pd, m);
  }
  if ((lane & 15) == 0) {
    int h = lane >> 4;
    a_s[n * NH + h] = ps;
    a_d[n * NH + h] = pd;
  }
}

// ---------------- per-dst-node softmax + weighted aggregation + head-mean ----------------
__global__ __launch_bounds__(256) void aggregate(const float* __restrict__ HP,
    const float* __restrict__ a_s, const float* __restrict__ a_d,
    const int* __restrict__ offs, const int* __restrict__ esrc,
    const float* __restrict__ gbias, float* __restrict__ hout)
{
  int lane = threadIdx.x & 63;
  int n = blockIdx.x * 4 + (threadIdx.x >> 6);
  int start = offs[n], end = offs[n + 1];
  float4 ad4 = *(const float4*)&a_d[n * NH];

  // pass A: per-head max over incident edges
  float4 m4 = make_float4(-1e30f, -1e30f, -1e30f, -1e30f);
  for (int j = start + lane; j < end; j += 64) {
    int s = esrc[j];
    float4 as4 = *(const float4*)&a_s[s * NH];
    m4.x = fmaxf(m4.x, lrelu(as4.x + ad4.x));
    m4.y = fmaxf(m4.y, lrelu(as4.y + ad4.y));
    m4.z = fmaxf(m4.z, lrelu(as4.z + ad4.z));
    m4.w = fmaxf(m4.w, lrelu(as4.w + ad4.w));
  }
  #pragma unroll
  for (int m = 1; m < 64; m <<= 1) {
    m4.x = fmaxf(m4.x, __shfl_xor(m4.x, m));
    m4.y = fmaxf(m4.y, __shfl_xor(m4.y, m));
    m4.z = fmaxf(m4.z, __shfl_xor(m4.z, m));
    m4.w = fmaxf(m4.w, __shfl_xor(m4.w, m));
  }
  float mh = (lane & 32) ? ((lane & 16) ? m4.w : m4.z) : ((lane & 16) ? m4.y : m4.x);
  float ad = (lane & 32) ? ((lane & 16) ? ad4.w : ad4.z) : ((lane & 16) ? ad4.y : ad4.x);
  int hsel = lane >> 4;

  // pass B: unnormalized weighted feature sum; denominator folded at the end
  float wsum = 0.f;
  float a0=0,a1=0,a2=0,a3=0,a4=0,a5=0,a6=0,a7=0;
  int di = lane * 8;
  for (int j = start; j < end; ++j) {
    int s = esrc[j];
    float e = lrelu(a_s[s * NH + hsel] + ad);
    float w = __expf(e - mh);
    wsum += w;
    const float4* hp = (const float4*)&HP[(size_t)s * HPD + di];
    float4 p0 = hp[0], p1 = hp[1];
    a0 = fmaf(w, p0.x, a0); a1 = fmaf(w, p0.y, a1);
    a2 = fmaf(w, p0.z, a2); a3 = fmaf(w, p0.w, a3);
    a4 = fmaf(w, p1.x, a4); a5 = fmaf(w, p1.y, a5);
    a6 = fmaf(w, p1.z, a6); a7 = fmaf(w, p1.w, a7);
  }
  float inv = 1.f / (wsum + 1e-16f);
  float r0=a0*inv, r1=a1*inv, r2=a2*inv, r3=a3*inv;
  float r4=a4*inv, r5=a5*inv, r6=a6*inv, r7=a7*inv;
  // mean over heads: lanes l, l^16, l^32, l^48 hold the 4 heads of the same d-slice
  #pragma unroll
  for (int m = 16; m <= 32; m <<= 1) {
    r0 += __shfl_xor(r0, m); r1 += __shfl_xor(r1, m);
    r2 += __shfl_xor(r2, m); r3 += __shfl_xor(r3, m);
    r4 += __shfl_xor(r4, m); r5 += __shfl_xor(r5, m);
    r6 += __shfl_xor(r6, m); r7 += __shfl_xor(r7, m);
  }
  if (lane < 16) {
    int dbase = lane * 8;
    const float4* gb = (const float4*)&gbias[dbase];
    float4 g0 = gb[0], g1 = gb[1];
    float4 o0 = make_float4(r0*0.25f + g0.x, r1*0.25f + g0.y, r2*0.25f + g0.z, r3*0.25f + g0.w);
    float4 o1 = make_float4(r4*0.25f + g1.x, r5*0.25f + g1.y, r6*0.25f + g1.z, r7*0.25f + g1.w);
    *(float4*)&hout[(size_t)n * DD + dbase] = o0;
    *(float4*)&hout[(size_t)n * DD + dbase + 4] = o1;
  }
}

// ---------------- batch norm ----------------
__global__ __launch_bounds__(128) void bn_stats(const float* __restrict__ h,
    float* __restrict__ bs, float* __restrict__ bq)
{
  int c = threadIdx.x;
  float s = 0.f, q = 0.f;
  for (int r = blockIdx.x; r < N_NODES; r += gridDim.x) {
    float v = h[(size_t)r * DD + c];
    s += v; q = fmaf(v, v, q);
  }
  atomicAdd(&bs[c], s);
  atomicAdd(&bq[c], q);
}

__global__ __launch_bounds__(256) void bn_apply(float* __restrict__ h,
    const float* __restrict__ bs, const float* __restrict__ bq,
    const float* __restrict__ g, const float* __restrict__ b)
{
  const float invN = 1.f / (float)N_NODES;
  int i4 = blockIdx.x * 256 + threadIdx.x;           // grid covers N*DD/4 exactly
  int c0 = (i4 * 4) & (DD - 1);
  float4 v = *(float4*)&h[(size_t)i4 * 4];
  float4 s = *(const float4*)&bs[c0];
  float4 q = *(const float4*)&bq[c0];
  float4 gg = *(const float4*)&g[c0];
  float4 bb = *(const float4*)&b[c0];
  float mu, var;
  mu = s.x * invN; var = q.x * invN - mu * mu;
  v.x = fmaxf((v.x - mu) * rsqrtf(var + EPS_BN) * gg.x + bb.x, 0.f);
  mu = s.y * invN; var = q.y * invN - mu * mu;
  v.y = fmaxf((v.y - mu) * rsqrtf(var + EPS_BN) * gg.y + bb.y, 0.f);
  mu = s.z * invN; var = q.z * invN - mu * mu;
  v.z = fmaxf((v.z - mu) * rsqrtf(var + EPS_BN) * gg.z + bb.z, 0.f);
  mu = s.w * invN; var = q.w * invN - mu * mu;
  v.w = fmaxf((v.w - mu) * rsqrtf(var + EPS_BN) * gg.w + bb.w, 0.f);
  *(float4*)&h[(size_t)i4 * 4] = v;
}

// ---------------- global mean pool (batch is sorted) ----------------
__global__ __launch_bounds__(256) void pool_kernel(const float* __restrict__ h,
    const int* __restrict__ batch, float* __restrict__ pooled)
{
  int g = blockIdx.x;
  int lo = 0, hi = N_NODES;
  while (lo < hi) { int mid = (lo + hi) >> 1; if (batch[mid] < g) lo = mid + 1; else hi = mid; }
  int start = lo;
  hi = N_NODES;
  while (lo < hi) { int mid = (lo + hi) >> 1; if (batch[mid] < g + 1) lo = mid + 1; else hi = mid; }
  int end = lo;
  int c = threadIdx.x & 127, ro = threadIdx.x >> 7;
  float s = 0.f;
  for (int r = start + ro; r < end; r += 2) s += h[(size_t)r * DD + c];
  __shared__ float red[256];
  red[threadIdx.x] = s;
  __syncthreads();
  if (ro == 0)
    pooled[g * DD + c] = (red[c] + red[128 + c]) / fmaxf((float)(end - start), 1.f);
}

// ---------------- MLP heads ----------------
__global__ __launch_bounds__(64) void heads_kernel(const float* __restrict__ pooled,
    const float* __restrict__ hw1, const float* __restrict__ hb1,
    const float* __restrict__ hw2, const float* __restrict__ hb2,
    float* __restrict__ out)
{
  int k = blockIdx.x >> 6;
  int g = blockIdx.x & 63;
  int o = threadIdx.x;
  const float4* p = (const float4*)&pooled[g * DD];
  const float4* w = (const float4*)&hw1[((size_t)k * 64 + o) * DD];
  float acc = hb1[k * 64 + o];
  #pragma unroll
  for (int d4 = 0; d4 < DD / 4; ++d4) {
    float4 pv = p[d4], wv = w[d4];
    acc += pv.x*wv.x + pv.y*wv.y + pv.z*wv.z + pv.w*wv.w;
  }
  float contrib = fmaxf(acc, 0.f) * hw2[k * 64 + o];
  #pragma unroll
  for (int m = 1; m < 64; m <<= 1) contrib += __shfl_xor(contrib, m);
  if (o == 0) out[g * 3 + k] = contrib + hb2[k];
}

extern "C" void kernel_launch(void* const* d_in, const int* in_sizes, int n_in,
                              void* d_out, int out_size, void* d_ws, size_t ws_size,
                              hipStream_t stream) {
  const float* x       = (const float*)d_in[0];
  const int*   ei      = (const int*)d_in[1];
  const int*   batch   = (const int*)d_in[2];
  const float* ip_w    = (const float*)d_in[3];
  const float* ip_b    = (const float*)d_in[4];
  const float* lin_w   = (const float*)d_in[5];
  const float* att_src = (const float*)d_in[6];
  const float* att_dst = (const float*)d_in[7];
  const float* gat_b   = (const float*)d_in[8];
  const float* bn_g    = (const float*)d_in[9];
  const float* bn_b    = (const float*)d_in[10];
  const float* hw1     = (const float*)d_in[11];
  const float* hb1     = (const float*)d_in[12];
  const float* hw2     = (const float*)d_in[13];
  const float* hb2     = (const float*)d_in[14];
  float* out = (float*)d_out;

  float* ws     = (float*)d_ws;
  float* h_a    = ws;
  float* h_b    = h_a + (size_t)N_NODES * DD;
  float* HP     = h_b + (size_t)N_NODES * DD;
  float* a_s    = HP + (size_t)N_NODES * HPD;
  float* a_d    = a_s + (size_t)N_NODES * NH;
  float* bnsum  = a_d + (size_t)N_NODES * NH;      // NL*DD
  float* bnss   = bnsum + NL * DD;                 // NL*DD
  float* pooled = bnss + NL * DD;                  // NGRAPH*DD
  int*   hist   = (int*)(pooled + NGRAPH * DD);
  int*   offs   = hist + (N_NODES + 4);
  int*   cursor = offs + (N_NODES + 4);
  int*   esrc   = cursor + (N_NODES + 4);

  hipMemsetAsync(hist, 0, N_NODES * sizeof(int), stream);
  hipMemsetAsync(bnsum, 0, 2 * NL * DD * sizeof(float), stream);

  hist_kernel<<<(ETOT + 255) / 256, 256, 0, stream>>>(ei, hist);
  scan_kernel<<<1, 1024, 0, stream>>>(hist, offs, cursor);
  scatter_kernel<<<(ETOT + 255) / 256, 256, 0, stream>>>(ei, cursor, esrc);

  // input projection + relu
  gemm_nt<<<dim3(DD / BN, (N_NODES + BM - 1) / BM), 256, 0, stream>>>(
      x, ip_w, h_a, N_NODES, DD, DIN, ip_b, 1);

  float* hin = h_a;
  float* hout = h_b;
  for (int l = 0; l < NL; ++l) {
    gemm_nt<<<dim3(HPD / BN, (N_NODES + BM - 1) / BM), 256, 0, stream>>>(
        hin, lin_w + (size_t)l * HPD * DD, HP, N_NODES, HPD, DD, nullptr, 0);
    attn_dots<<<N_NODES / 4, 256, 0, stream>>>(
        HP, att_src + (size_t)l * HPD, att_dst + (size_t)l * HPD, a_s, a_d);
    aggregate<<<N_NODES / 4, 256, 0, stream>>>(
        HP, a_s, a_d, offs, esrc, gat_b + (size_t)l * DD, hout);
    bn_stats<<<256, 128, 0, stream>>>(hout, bnsum + l * DD, bnss + l * DD);
    bn_apply<<<(N_NODES * DD / 4) / 256, 256, 0, stream>>>(
        hout, bnsum + l * DD, bnss + l * DD, bn_g + (size_t)l * DD, bn_b + (size_t)l * DD);
    float* t = hin; hin = hout; hout = t;
  }

  pool_kernel<<<NGRAPH, 256, 0, stream>>>(hin, batch, pooled);
  heads_kernel<<<NL * NGRAPH, 64, 0, stream>>>(pooled, hw1, hb1, hw2, hb2, out);
}

// Round 5
// 645.412 us; speedup vs baseline: 1.2658x; 1.2658x over previous
//
#include <hip/hip_runtime.h>
#include <math.h>

#define N_NODES 20000
#define N_EDGES 320000
#define ETOT    (N_EDGES + N_NODES)
#define NGRAPH  64
#define DIN     256
#define DD      128
#define NH      4
#define NL      3
#define HPD     (NH*DD)   // 512
#define EPS_BN  1e-5f
#define SLOPE   0.2f

__device__ __forceinline__ float lrelu(float x) { return x >= 0.f ? x : SLOPE * x; }

__device__ __forceinline__ unsigned short f2bf(float f) {  // RTNE
  unsigned u = __float_as_uint(f);
  unsigned r = (u + 0x7FFFu + ((u >> 16) & 1u)) >> 16;
  return (unsigned short)r;
}
__device__ __forceinline__ void bf2x(unsigned u, float& lo, float& hi) {
  lo = __uint_as_float(u << 16);
  hi = __uint_as_float(u & 0xFFFF0000u);
}

// ---------------- CSR build ----------------
__global__ void hist_kernel(const int* __restrict__ ei, int* __restrict__ hist) {
  int idx = blockIdx.x * 256 + threadIdx.x;
  if (idx >= ETOT) return;
  int d = (idx < N_EDGES) ? ei[N_EDGES + idx] : (idx - N_EDGES);
  atomicAdd(&hist[d], 1);
}

__global__ __launch_bounds__(1024) void scan_kernel(const int* __restrict__ hist,
                                                    int* __restrict__ offs,
                                                    int* __restrict__ cursor) {
  __shared__ int wsum[16];
  int tid = threadIdx.x, lane = tid & 63, wid = tid >> 6;
  int carry = 0;
  for (int base = 0; base < N_NODES; base += 1024) {
    int i = base + tid;
    int x = (i < N_NODES) ? hist[i] : 0;
    int v = x;
    #pragma unroll
    for (int d = 1; d < 64; d <<= 1) {
      int t = __shfl_up(v, d);
      if (lane >= d) v += t;
    }
    if (lane == 63) wsum[wid] = v;
    __syncthreads();
    if (wid == 0) {
      int sv = (lane < 16) ? wsum[lane] : 0;
      #pragma unroll
      for (int d = 1; d < 16; d <<= 1) {
        int t = __shfl_up(sv, d);
        if (lane >= d) sv += t;
      }
      if (lane < 16) wsum[lane] = sv;
    }
    __syncthreads();
    int woff = (wid > 0) ? wsum[wid - 1] : 0;
    int incl = carry + woff + v;
    if (i < N_NODES) { int e = incl - x; offs[i] = e; cursor[i] = e; }
    carry += wsum[15];
    __syncthreads();
  }
  if (tid == 0) offs[N_NODES] = carry;
}

__global__ void scatter_kernel(const int* __restrict__ ei, int* __restrict__ cursor,
                               int* __restrict__ esrc) {
  int idx = blockIdx.x * 256 + threadIdx.x;
  if (idx >= ETOT) return;
  int s, d;
  if (idx < N_EDGES) { s = ei[idx]; d = ei[N_EDGES + idx]; }
  else { s = idx - N_EDGES; d = s; }
  int pos = atomicAdd(&cursor[d], 1);
  esrc[pos] = s;
}

// ---------------- GEMM NT: C[M,Nc] = act(A[M,K] @ B[Nc,K]^T + bias) ----------------
// C (fp32) and/or Cb (bf16) outputs; either may be null.
#define BM 64
#define BN 64
#define BKK 128

__global__ __launch_bounds__(256) void gemm_nt(const float* __restrict__ A,
    const float* __restrict__ B, float* __restrict__ C, unsigned short* __restrict__ Cb,
    int M, int Nc, int K, const float* __restrict__ bias, int do_relu)
{
  __shared__ float As[BM][BKK];
  __shared__ float Bs[BN][BKK];
  int tid = threadIdx.x;
  int m0 = blockIdx.y * BM, n0 = blockIdx.x * BN;
  int ty = tid >> 4, tx = tid & 15;
  float acc[4][4];
  #pragma unroll
  for (int i = 0; i < 4; ++i)
    #pragma unroll
    for (int j = 0; j < 4; ++j) acc[i][j] = 0.f;

  const int swA = ty & 7;
  const int swB = tx & 7;

  for (int kc = 0; kc < K; kc += BKK) {
    __syncthreads();
    #pragma unroll
    for (int i = 0; i < 8; ++i) {
      int f4 = tid + i * 256;
      int row = f4 >> 5, c4 = f4 & 31;
      int sw = c4 ^ ((row >> 2) & 7);
      int gr = m0 + row;
      float4 va = make_float4(0.f, 0.f, 0.f, 0.f);
      if (gr < M) va = *(const float4*)&A[(size_t)gr * K + kc + c4 * 4];
      *(float4*)&As[row][sw * 4] = va;
      int gb = n0 + row;
      float4 vb = *(const float4*)&B[(size_t)gb * K + kc + c4 * 4];
      *(float4*)&Bs[row][sw * 4] = vb;
    }
    __syncthreads();
    #pragma unroll 8
    for (int k4 = 0; k4 < BKK / 4; ++k4) {
      float4 av[4], bv[4];
      int ca = (k4 ^ swA) * 4;
      int cb = (k4 ^ swB) * 4;
      #pragma unroll
      for (int i = 0; i < 4; ++i) av[i] = *(const float4*)&As[ty * 4 + i][ca];
      #pragma unroll
      for (int j = 0; j < 4; ++j) bv[j] = *(const float4*)&Bs[tx * 4 + j][cb];
      #pragma unroll
      for (int i = 0; i < 4; ++i)
        #pragma unroll
        for (int j = 0; j < 4; ++j) {
          acc[i][j] = fmaf(av[i].x, bv[j].x, acc[i][j]);
          acc[i][j] = fmaf(av[i].y, bv[j].y, acc[i][j]);
          acc[i][j] = fmaf(av[i].z, bv[j].z, acc[i][j]);
          acc[i][j] = fmaf(av[i].w, bv[j].w, acc[i][j]);
        }
    }
  }
  int ncol = n0 + tx * 4;
  float4 bz = make_float4(0.f, 0.f, 0.f, 0.f);
  if (bias) bz = *(const float4*)&bias[ncol];
  #pragma unroll
  for (int i = 0; i < 4; ++i) {
    int gr = m0 + ty * 4 + i;
    if (gr < M) {
      float4 o;
      o.x = acc[i][0] + bz.x; o.y = acc[i][1] + bz.y;
      o.z = acc[i][2] + bz.z; o.w = acc[i][3] + bz.w;
      if (do_relu) {
        o.x = fmaxf(o.x, 0.f); o.y = fmaxf(o.y, 0.f);
        o.z = fmaxf(o.z, 0.f); o.w = fmaxf(o.w, 0.f);
      }
      if (C) *(float4*)&C[(size_t)gr * Nc + ncol] = o;
      if (Cb) {
        ushort4 ob;
        ob.x = f2bf(o.x); ob.y = f2bf(o.y); ob.z = f2bf(o.z); ob.w = f2bf(o.w);
        *(ushort4*)&Cb[(size_t)gr * Nc + ncol] = ob;
      }
    }
  }
}

// ---------------- attention dot products (bf16 h): a_src/a_dst [N,4] ----------------
__global__ __launch_bounds__(256) void attn_dots(const unsigned short* __restrict__ HPh,
    const float* __restrict__ atts, const float* __restrict__ attd,
    float* __restrict__ a_s, float* __restrict__ a_d)
{
  int lane = threadIdx.x & 63;
  int n = blockIdx.x * 4 + (threadIdx.x >> 6);
  uint4 u = *(const uint4*)&HPh[(size_t)n * HPD + lane * 8];
  float p0, p1, p2, p3, p4, p5, p6, p7;
  bf2x(u.x, p0, p1); bf2x(u.y, p2, p3); bf2x(u.z, p4, p5); bf2x(u.w, p6, p7);
  const float4* wsv = (const float4*)&atts[lane * 8];
  float4 s0 = wsv[0], s1 = wsv[1];
  const float4* wdv = (const float4*)&attd[lane * 8];
  float4 d0 = wdv[0], d1 = wdv[1];
  float ps = p0*s0.x + p1*s0.y + p2*s0.z + p3*s0.w
           + p4*s1.x + p5*s1.y + p6*s1.z + p7*s1.w;
  float pd = p0*d0.x + p1*d0.y + p2*d0.z + p3*d0.w
           + p4*d1.x + p5*d1.y + p6*d1.z + p7*d1.w;
  #pragma unroll
  for (int m = 1; m <= 8; m <<= 1) {
    ps += __shfl_xor(ps, m);
    pd += __shfl_xor(pd, m);
  }
  if ((lane & 15) == 0) {
    int h = lane >> 4;
    a_s[n * NH + h] = ps;
    a_d[n * NH + h] = pd;
  }
}

// ---------------- per-dst softmax + weighted aggregation + head-mean ----------------
// One wave per dst node. Edge weights computed lane-parallel, broadcast by
// v_readlane in the payload loop so the only per-iteration memory op is the
// independent 16B bf16 gather.
__global__ __launch_bounds__(256) void aggregate(const unsigned short* __restrict__ HPh,
    const float* __restrict__ a_s, const float* __restrict__ a_d,
    const int* __restrict__ offs, const int* __restrict__ esrc,
    const float* __restrict__ gbias, float* __restrict__ hout)
{
  int lane = threadIdx.x & 63;
  int n = blockIdx.x * 4 + (threadIdx.x >> 6);
  int start = offs[n], end = offs[n + 1];
  float4 ad4 = *(const float4*)&a_d[n * NH];
  int hsel = lane >> 4;
  int di = lane * 8;

  // phase 1: per-head max over incident edges
  float4 m4 = make_float4(-1e30f, -1e30f, -1e30f, -1e30f);
  for (int j = start + lane; j < end; j += 64) {
    int s = esrc[j];
    float4 as4 = *(const float4*)&a_s[s * NH];
    m4.x = fmaxf(m4.x, lrelu(as4.x + ad4.x));
    m4.y = fmaxf(m4.y, lrelu(as4.y + ad4.y));
    m4.z = fmaxf(m4.z, lrelu(as4.z + ad4.z));
    m4.w = fmaxf(m4.w, lrelu(as4.w + ad4.w));
  }
  #pragma unroll
  for (int m = 1; m < 64; m <<= 1) {
    m4.x = fmaxf(m4.x, __shfl_xor(m4.x, m));
    m4.y = fmaxf(m4.y, __shfl_xor(m4.y, m));
    m4.z = fmaxf(m4.z, __shfl_xor(m4.z, m));
    m4.w = fmaxf(m4.w, __shfl_xor(m4.w, m));
  }

  // phase 2: weights in parallel, payload gather serial with readlane broadcast
  float4 wacc = make_float4(0.f, 0.f, 0.f, 0.f);
  float a0=0,a1=0,a2=0,a3=0,a4=0,a5=0,a6=0,a7=0;
  for (int base = start; base < end; base += 64) {
    int j = base + lane;
    float4 w4 = make_float4(0.f, 0.f, 0.f, 0.f);
    int s = 0;
    if (j < end) {
      s = esrc[j];
      float4 as4 = *(const float4*)&a_s[s * NH];
      w4.x = __expf(lrelu(as4.x + ad4.x) - m4.x);
      w4.y = __expf(lrelu(as4.y + ad4.y) - m4.y);
      w4.z = __expf(lrelu(as4.z + ad4.z) - m4.z);
      w4.w = __expf(lrelu(as4.w + ad4.w) - m4.w);
    }
    wacc.x += w4.x; wacc.y += w4.y; wacc.z += w4.z; wacc.w += w4.w;
    int cnt = min(64, end - base);
    for (int t = 0; t < cnt; ++t) {
      int sj = __shfl(s, t);
      float wx = __shfl(w4.x, t), wy = __shfl(w4.y, t);
      float wz = __shfl(w4.z, t), ww = __shfl(w4.w, t);
      float wj = (hsel == 0) ? wx : (hsel == 1) ? wy : (hsel == 2) ? wz : ww;
      uint4 u = *(const uint4*)&HPh[(size_t)sj * HPD + di];
      float f0, f1, f2, f3, f4, f5, f6, f7;
      bf2x(u.x, f0, f1); bf2x(u.y, f2, f3); bf2x(u.z, f4, f5); bf2x(u.w, f6, f7);
      a0 = fmaf(wj, f0, a0); a1 = fmaf(wj, f1, a1);
      a2 = fmaf(wj, f2, a2); a3 = fmaf(wj, f3, a3);
      a4 = fmaf(wj, f4, a4); a5 = fmaf(wj, f5, a5);
      a6 = fmaf(wj, f6, a6); a7 = fmaf(wj, f7, a7);
    }
  }
  #pragma unroll
  for (int m = 1; m < 64; m <<= 1) {
    wacc.x += __shfl_xor(wacc.x, m);
    wacc.y += __shfl_xor(wacc.y, m);
    wacc.z += __shfl_xor(wacc.z, m);
    wacc.w += __shfl_xor(wacc.w, m);
  }
  float wsum = (hsel == 0) ? wacc.x : (hsel == 1) ? wacc.y : (hsel == 2) ? wacc.z : wacc.w;
  float inv = 1.f / (wsum + 1e-16f);
  float r0=a0*inv, r1=a1*inv, r2=a2*inv, r3=a3*inv;
  float r4=a4*inv, r5=a5*inv, r6=a6*inv, r7=a7*inv;
  #pragma unroll
  for (int m = 16; m <= 32; m <<= 1) {
    r0 += __shfl_xor(r0, m); r1 += __shfl_xor(r1, m);
    r2 += __shfl_xor(r2, m); r3 += __shfl_xor(r3, m);
    r4 += __shfl_xor(r4, m); r5 += __shfl_xor(r5, m);
    r6 += __shfl_xor(r6, m); r7 += __shfl_xor(r7, m);
  }
  if (lane < 16) {
    int dbase = lane * 8;
    const float4* gb = (const float4*)&gbias[dbase];
    float4 g0 = gb[0], g1 = gb[1];
    float4 o0 = make_float4(r0*0.25f + g0.x, r1*0.25f + g0.y, r2*0.25f + g0.z, r3*0.25f + g0.w);
    float4 o1 = make_float4(r4*0.25f + g1.x, r5*0.25f + g1.y, r6*0.25f + g1.z, r7*0.25f + g1.w);
    *(float4*)&hout[(size_t)n * DD + dbase] = o0;
    *(float4*)&hout[(size_t)n * DD + dbase + 4] = o1;
  }
}

// ---------------- batch norm ----------------
__global__ __launch_bounds__(128) void bn_stats(const float* __restrict__ h,
    float* __restrict__ bs, float* __restrict__ bq)
{
  int c = threadIdx.x;
  float s = 0.f, q = 0.f;
  for (int r = blockIdx.x; r < N_NODES; r += gridDim.x) {
    float v = h[(size_t)r * DD + c];
    s += v; q = fmaf(v, v, q);
  }
  atomicAdd(&bs[c], s);
  atomicAdd(&bq[c], q);
}

__global__ __launch_bounds__(256) void bn_apply(float* __restrict__ h,
    const float* __restrict__ bs, const float* __restrict__ bq,
    const float* __restrict__ g, const float* __restrict__ b)
{
  const float invN = 1.f / (float)N_NODES;
  int i4 = blockIdx.x * 256 + threadIdx.x;
  int c0 = (i4 * 4) & (DD - 1);
  float4 v = *(float4*)&h[(size_t)i4 * 4];
  float4 s = *(const float4*)&bs[c0];
  float4 q = *(const float4*)&bq[c0];
  float4 gg = *(const float4*)&g[c0];
  float4 bb = *(const float4*)&b[c0];
  float mu, var;
  mu = s.x * invN; var = q.x * invN - mu * mu;
  v.x = fmaxf((v.x - mu) * rsqrtf(var + EPS_BN) * gg.x + bb.x, 0.f);
  mu = s.y * invN; var = q.y * invN - mu * mu;
  v.y = fmaxf((v.y - mu) * rsqrtf(var + EPS_BN) * gg.y + bb.y, 0.f);
  mu = s.z * invN; var = q.z * invN - mu * mu;
  v.z = fmaxf((v.z - mu) * rsqrtf(var + EPS_BN) * gg.z + bb.z, 0.f);
  mu = s.w * invN; var = q.w * invN - mu * mu;
  v.w = fmaxf((v.w - mu) * rsqrtf(var + EPS_BN) * gg.w + bb.w, 0.f);
  *(float4*)&h[(size_t)i4 * 4] = v;
}

// ---------------- global mean pool (batch sorted) ----------------
__global__ __launch_bounds__(256) void pool_kernel(const float* __restrict__ h,
    const int* __restrict__ batch, float* __restrict__ pooled)
{
  int g = blockIdx.x;
  int lo = 0, hi = N_NODES;
  while (lo < hi) { int mid = (lo + hi) >> 1; if (batch[mid] < g) lo = mid + 1; else hi = mid; }
  int start = lo;
  hi = N_NODES;
  while (lo < hi) { int mid = (lo + hi) >> 1; if (batch[mid] < g + 1) lo = mid + 1; else hi = mid; }
  int end = lo;
  int c = threadIdx.x & 127, ro = threadIdx.x >> 7;
  float s = 0.f;
  for (int r = start + ro; r < end; r += 2) s += h[(size_t)r * DD + c];
  __shared__ float red[256];
  red[threadIdx.x] = s;
  __syncthreads();
  if (ro == 0)
    pooled[g * DD + c] = (red[c] + red[128 + c]) / fmaxf((float)(end - start), 1.f);
}

// ---------------- MLP heads ----------------
__global__ __launch_bounds__(64) void heads_kernel(const float* __restrict__ pooled,
    const float* __restrict__ hw1, const float* __restrict__ hb1,
    const float* __restrict__ hw2, const float* __restrict__ hb2,
    float* __restrict__ out)
{
  int k = blockIdx.x >> 6;
  int g = blockIdx.x & 63;
  int o = threadIdx.x;
  const float4* p = (const float4*)&pooled[g * DD];
  const float4* w = (const float4*)&hw1[((size_t)k * 64 + o) * DD];
  float acc = hb1[k * 64 + o];
  #pragma unroll
  for (int d4 = 0; d4 < DD / 4; ++d4) {
    float4 pv = p[d4], wv = w[d4];
    acc += pv.x*wv.x + pv.y*wv.y + pv.z*wv.z + pv.w*wv.w;
  }
  float contrib = fmaxf(acc, 0.f) * hw2[k * 64 + o];
  #pragma unroll
  for (int m = 1; m < 64; m <<= 1) contrib += __shfl_xor(contrib, m);
  if (o == 0) out[g * 3 + k] = contrib + hb2[k];
}

extern "C" void kernel_launch(void* const* d_in, const int* in_sizes, int n_in,
                              void* d_out, int out_size, void* d_ws, size_t ws_size,
                              hipStream_t stream) {
  const float* x       = (const float*)d_in[0];
  const int*   ei      = (const int*)d_in[1];
  const int*   batch   = (const int*)d_in[2];
  const float* ip_w    = (const float*)d_in[3];
  const float* ip_b    = (const float*)d_in[4];
  const float* lin_w   = (const float*)d_in[5];
  const float* att_src = (const float*)d_in[6];
  const float* att_dst = (const float*)d_in[7];
  const float* gat_b   = (const float*)d_in[8];
  const float* bn_g    = (const float*)d_in[9];
  const float* bn_b    = (const float*)d_in[10];
  const float* hw1     = (const float*)d_in[11];
  const float* hb1     = (const float*)d_in[12];
  const float* hw2     = (const float*)d_in[13];
  const float* hb2     = (const float*)d_in[14];
  float* out = (float*)d_out;

  float* ws     = (float*)d_ws;
  float* h_a    = ws;
  float* h_b    = h_a + (size_t)N_NODES * DD;
  float* a_s    = h_b + (size_t)N_NODES * DD;
  float* a_d    = a_s + (size_t)N_NODES * NH;
  float* bnsum  = a_d + (size_t)N_NODES * NH;      // NL*DD
  float* bnss   = bnsum + NL * DD;                 // NL*DD
  float* pooled = bnss + NL * DD;                  // NGRAPH*DD
  unsigned short* HPh = (unsigned short*)(pooled + NGRAPH * DD);  // N*HPD bf16
  int*   hist   = (int*)(HPh + (size_t)N_NODES * HPD);
  int*   offs   = hist + (N_NODES + 4);
  int*   cursor = offs + (N_NODES + 4);
  int*   esrc   = cursor + (N_NODES + 4);

  hipMemsetAsync(hist, 0, N_NODES * sizeof(int), stream);
  hipMemsetAsync(bnsum, 0, 2 * NL * DD * sizeof(float), stream);

  hist_kernel<<<(ETOT + 255) / 256, 256, 0, stream>>>(ei, hist);
  scan_kernel<<<1, 1024, 0, stream>>>(hist, offs, cursor);
  scatter_kernel<<<(ETOT + 255) / 256, 256, 0, stream>>>(ei, cursor, esrc);

  // input projection + relu (fp32 out)
  gemm_nt<<<dim3(DD / BN, (N_NODES + BM - 1) / BM), 256, 0, stream>>>(
      x, ip_w, h_a, nullptr, N_NODES, DD, DIN, ip_b, 1);

  float* hin = h_a;
  float* hout = h_b;
  for (int l = 0; l < NL; ++l) {
    // layer projection -> bf16 HPh only
    gemm_nt<<<dim3(HPD / BN, (N_NODES + BM - 1) / BM), 256, 0, stream>>>(
        hin, lin_w + (size_t)l * HPD * DD, nullptr, HPh, N_NODES, HPD, DD, nullptr, 0);
    attn_dots<<<N_NODES / 4, 256, 0, stream>>>(
        HPh, att_src + (size_t)l * HPD, att_dst + (size_t)l * HPD, a_s, a_d);
    aggregate<<<N_NODES / 4, 256, 0, stream>>>(
        HPh, a_s, a_d, offs, esrc, gat_b + (size_t)l * DD, hout);
    bn_stats<<<256, 128, 0, stream>>>(hout, bnsum + l * DD, bnss + l * DD);
    bn_apply<<<(N_NODES * DD / 4) / 256, 256, 0, stream>>>(
        hout, bnsum + l * DD, bnss + l * DD, bn_g + (size_t)l * DD, bn_b + (size_t)l * DD);
    float* t = hin; hin = hout; hout = t;
  }

  pool_kernel<<<NGRAPH, 256, 0, stream>>>(hin, batch, pooled);
  heads_kernel<<<NL * NGRAPH, 64, 0, stream>>>(pooled, hw1, hb1, hw2, hb2, out);
}

// Round 7
// 523.563 us; speedup vs baseline: 1.5604x; 1.2327x over previous
//
#include <hip/hip_runtime.h>
#include <math.h>

#define N_NODES 20000
#define N_EDGES 320000
#define ETOT    (N_EDGES + N_NODES)
#define NGRAPH  64
#define DIN     256
#define DD      128
#define NH      4
#define NL      3
#define HPD     (NH*DD)   // 512
#define EPS_BN  1e-5f
#define SLOPE   0.2f

typedef __attribute__((ext_vector_type(8))) short short8;   // 8 bf16 (4 VGPRs)
typedef __attribute__((ext_vector_type(4))) float f32x4;    // MFMA acc

__device__ __forceinline__ float lrelu(float x) { return x >= 0.f ? x : SLOPE * x; }

__device__ __forceinline__ unsigned short f2bf(float f) {  // RTNE
  unsigned u = __float_as_uint(f);
  unsigned r = (u + 0x7FFFu + ((u >> 16) & 1u)) >> 16;
  return (unsigned short)r;
}
__device__ __forceinline__ float bf2f(unsigned short b) {
  return __uint_as_float((unsigned)b << 16);
}
__device__ __forceinline__ void bf2x(unsigned u, float& lo, float& hi) {
  lo = __uint_as_float(u << 16);
  hi = __uint_as_float(u & 0xFFFF0000u);
}

// ---------------- fp32 -> bf16 conversion (n divisible by 4) ----------------
__global__ void f2bf_kernel(const float* __restrict__ in, unsigned short* __restrict__ out, int n4) {
  int i = blockIdx.x * 256 + threadIdx.x;
  if (i >= n4) return;
  float4 v = *(const float4*)&in[(size_t)i * 4];
  ushort4 o;
  o.x = f2bf(v.x); o.y = f2bf(v.y); o.z = f2bf(v.z); o.w = f2bf(v.w);
  *(ushort4*)&out[(size_t)i * 4] = o;
}

// ---------------- CSR build ----------------
__global__ void hist_kernel(const int* __restrict__ ei, int* __restrict__ hist) {
  int idx = blockIdx.x * 256 + threadIdx.x;
  if (idx >= ETOT) return;
  int d = (idx < N_EDGES) ? ei[N_EDGES + idx] : (idx - N_EDGES);
  atomicAdd(&hist[d], 1);
}

__global__ __launch_bounds__(1024) void scan_kernel(const int* __restrict__ hist,
                                                    int* __restrict__ offs,
                                                    int* __restrict__ cursor) {
  __shared__ int wsum[16];
  int tid = threadIdx.x, lane = tid & 63, wid = tid >> 6;
  int carry = 0;
  for (int base = 0; base < N_NODES; base += 1024) {
    int i = base + tid;
    int x = (i < N_NODES) ? hist[i] : 0;
    int v = x;
    #pragma unroll
    for (int d = 1; d < 64; d <<= 1) {
      int t = __shfl_up(v, d);
      if (lane >= d) v += t;
    }
    if (lane == 63) wsum[wid] = v;
    __syncthreads();
    if (wid == 0) {
      int sv = (lane < 16) ? wsum[lane] : 0;
      #pragma unroll
      for (int d = 1; d < 16; d <<= 1) {
        int t = __shfl_up(sv, d);
        if (lane >= d) sv += t;
      }
      if (lane < 16) wsum[lane] = sv;
    }
    __syncthreads();
    int woff = (wid > 0) ? wsum[wid - 1] : 0;
    int incl = carry + woff + v;
    if (i < N_NODES) { int e = incl - x; offs[i] = e; cursor[i] = e; }
    carry += wsum[15];
    __syncthreads();
  }
  if (tid == 0) offs[N_NODES] = carry;
}

__global__ void scatter_kernel(const int* __restrict__ ei, int* __restrict__ cursor,
                               int* __restrict__ esrc) {
  int idx = blockIdx.x * 256 + threadIdx.x;
  if (idx >= ETOT) return;
  int s, d;
  if (idx < N_EDGES) { s = ei[idx]; d = ei[N_EDGES + idx]; }
  else { s = idx - N_EDGES; d = s; }
  int pos = atomicAdd(&cursor[d], 1);
  esrc[pos] = s;
}

// ---------------- MFMA bf16 GEMM NT: C[M,Nc] = act(A[M,K] @ B[Nc,K]^T + bias) ----
// No LDS: fragments load direct from global (L1/L2-hot operands), register
// double-buffer over K. Block 128x128 = 2x2 waves of 64x64; Nc % 128 == 0.
// mfma_f32_16x16x32_bf16 layout: A lane holds row=lane&15, k=(lane>>4)*8+j;
// B lane holds col=lane&15, same k; D: row=(lane>>4)*4+reg, col=lane&15.
__global__ __launch_bounds__(256) void gemm_mfma_nt(
    const unsigned short* __restrict__ A,  // [M,K] bf16 row-major
    const unsigned short* __restrict__ B,  // [Nc,K] bf16 row-major
    unsigned short* __restrict__ Cb,       // [M,Nc] bf16 out
    int M, int Nc, int K,
    const float* __restrict__ bias, int do_relu)
{
  int lane = threadIdx.x & 63;
  int wid  = threadIdx.x >> 6;
  int wm = wid >> 1, wn = wid & 1;
  int m0 = blockIdx.y * 128 + wm * 64;
  int n0 = blockIdx.x * 128 + wn * 64;
  int lr = lane & 15;
  int kg = lane >> 4;      // k-group: k-offset kg*8

  f32x4 acc[4][4];
  #pragma unroll
  for (int i = 0; i < 4; ++i)
    #pragma unroll
    for (int j = 0; j < 4; ++j)
      acc[i][j] = (f32x4){0.f, 0.f, 0.f, 0.f};

  size_t abase[4], bbase[4];
  #pragma unroll
  for (int i = 0; i < 4; ++i) {
    int ar = m0 + i * 16 + lr;
    if (ar >= M) ar = M - 1;              // M-tail clamp (stores predicated)
    abase[i] = (size_t)ar * K;
    bbase[i] = (size_t)(n0 + i * 16 + lr) * K;
  }

  int nk = K >> 5;
  short8 afr[4], bfr[4], a2[4], b2[4];
  #pragma unroll
  for (int i = 0; i < 4; ++i) {
    afr[i] = *(const short8*)&A[abase[i] + kg * 8];
    bfr[i] = *(const short8*)&B[bbase[i] + kg * 8];
  }
  for (int ks = 0; ks < nk; ++ks) {
    if (ks + 1 < nk) {
      int ko = (ks + 1) * 32 + kg * 8;
      #pragma unroll
      for (int i = 0; i < 4; ++i) {
        a2[i] = *(const short8*)&A[abase[i] + ko];
        b2[i] = *(const short8*)&B[bbase[i] + ko];
      }
    }
    #pragma unroll
    for (int i = 0; i < 4; ++i)
      #pragma unroll
      for (int j = 0; j < 4; ++j)
        acc[i][j] = __builtin_amdgcn_mfma_f32_16x16x32_bf16(afr[i], bfr[j], acc[i][j], 0, 0, 0);
    if (ks + 1 < nk) {
      #pragma unroll
      for (int i = 0; i < 4; ++i) { afr[i] = a2[i]; bfr[i] = b2[i]; }
    }
  }

  // epilogue: D row=(lane>>4)*4+r, col=lane&15 within each 16x16 frag
  float bz[4];
  #pragma unroll
  for (int j = 0; j < 4; ++j)
    bz[j] = bias ? bias[n0 + j * 16 + lr] : 0.f;
  #pragma unroll
  for (int i = 0; i < 4; ++i) {
    #pragma unroll
    for (int r = 0; r < 4; ++r) {
      int row = m0 + i * 16 + kg * 4 + r;
      if (row < M) {
        size_t rb = (size_t)row * Nc;
        #pragma unroll
        for (int j = 0; j < 4; ++j) {
          float v = acc[i][j][r] + bz[j];
          if (do_relu) v = fmaxf(v, 0.f);
          Cb[rb + n0 + j * 16 + lr] = f2bf(v);
        }
      }
    }
  }
}

// ---------------- attention dot products (bf16 h): a_src/a_dst [N,4] ----------------
__global__ __launch_bounds__(256) void attn_dots(const unsigned short* __restrict__ HPh,
    const float* __restrict__ atts, const float* __restrict__ attd,
    float* __restrict__ a_s, float* __restrict__ a_d)
{
  int lane = threadIdx.x & 63;
  int n = blockIdx.x * 4 + (threadIdx.x >> 6);
  uint4 u = *(const uint4*)&HPh[(size_t)n * HPD + lane * 8];
  float p0, p1, p2, p3, p4, p5, p6, p7;
  bf2x(u.x, p0, p1); bf2x(u.y, p2, p3); bf2x(u.z, p4, p5); bf2x(u.w, p6, p7);
  const float4* wsv = (const float4*)&atts[lane * 8];
  float4 s0 = wsv[0], s1 = wsv[1];
  const float4* wdv = (const float4*)&attd[lane * 8];
  float4 d0 = wdv[0], d1 = wdv[1];
  float ps = p0*s0.x + p1*s0.y + p2*s0.z + p3*s0.w
           + p4*s1.x + p5*s1.y + p6*s1.z + p7*s1.w;
  float pd = p0*d0.x + p1*d0.y + p2*d0.z + p3*d0.w
           + p4*d1.x + p5*d1.y + p6*d1.z + p7*d1.w;
  #pragma unroll
  for (int m = 1; m <= 8; m <<= 1) {
    ps += __shfl_xor(ps, m);
    pd += __shfl_xor(pd, m);
  }
  if ((lane & 15) == 0) {
    int h = lane >> 4;
    a_s[n * NH + h] = ps;
    a_d[n * NH + h] = pd;
  }
}

// ---------------- per-dst softmax + weighted aggregation + head-mean ----------------
__global__ __launch_bounds__(256) void aggregate(const unsigned short* __restrict__ HPh,
    const float* __restrict__ a_s, const float* __restrict__ a_d,
    const int* __restrict__ offs, const int* __restrict__ esrc,
    const float* __restrict__ gbias, float* __restrict__ hout)
{
  int lane = threadIdx.x & 63;
  int n = blockIdx.x * 4 + (threadIdx.x >> 6);
  int start = offs[n], end = offs[n + 1];
  float4 ad4 = *(const float4*)&a_d[n * NH];
  int hsel = lane >> 4;
  int di = lane * 8;

  float4 m4 = make_float4(-1e30f, -1e30f, -1e30f, -1e30f);
  for (int j = start + lane; j < end; j += 64) {
    int s = esrc[j];
    float4 as4 = *(const float4*)&a_s[s * NH];
    m4.x = fmaxf(m4.x, lrelu(as4.x + ad4.x));
    m4.y = fmaxf(m4.y, lrelu(as4.y + ad4.y));
    m4.z = fmaxf(m4.z, lrelu(as4.z + ad4.z));
    m4.w = fmaxf(m4.w, lrelu(as4.w + ad4.w));
  }
  #pragma unroll
  for (int m = 1; m < 64; m <<= 1) {
    m4.x = fmaxf(m4.x, __shfl_xor(m4.x, m));
    m4.y = fmaxf(m4.y, __shfl_xor(m4.y, m));
    m4.z = fmaxf(m4.z, __shfl_xor(m4.z, m));
    m4.w = fmaxf(m4.w, __shfl_xor(m4.w, m));
  }

  float4 wacc = make_float4(0.f, 0.f, 0.f, 0.f);
  float a0=0,a1=0,a2=0,a3=0,a4=0,a5=0,a6=0,a7=0;
  for (int base = start; base < end; base += 64) {
    int j = base + lane;
    float4 w4 = make_float4(0.f, 0.f, 0.f, 0.f);
    int s = 0;
    if (j < end) {
      s = esrc[j];
      float4 as4 = *(const float4*)&a_s[s * NH];
      w4.x = __expf(lrelu(as4.x + ad4.x) - m4.x);
      w4.y = __expf(lrelu(as4.y + ad4.y) - m4.y);
      w4.z = __expf(lrelu(as4.z + ad4.z) - m4.z);
      w4.w = __expf(lrelu(as4.w + ad4.w) - m4.w);
    }
    wacc.x += w4.x; wacc.y += w4.y; wacc.z += w4.z; wacc.w += w4.w;
    int cnt = min(64, end - base);
    for (int t = 0; t < cnt; ++t) {
      int sj = __shfl(s, t);
      float wx = __shfl(w4.x, t), wy = __shfl(w4.y, t);
      float wz = __shfl(w4.z, t), ww = __shfl(w4.w, t);
      float wj = (hsel == 0) ? wx : (hsel == 1) ? wy : (hsel == 2) ? wz : ww;
      uint4 u = *(const uint4*)&HPh[(size_t)sj * HPD + di];
      float f0, f1, f2, f3, f4, f5, f6, f7;
      bf2x(u.x, f0, f1); bf2x(u.y, f2, f3); bf2x(u.z, f4, f5); bf2x(u.w, f6, f7);
      a0 = fmaf(wj, f0, a0); a1 = fmaf(wj, f1, a1);
      a2 = fmaf(wj, f2, a2); a3 = fmaf(wj, f3, a3);
      a4 = fmaf(wj, f4, a4); a5 = fmaf(wj, f5, a5);
      a6 = fmaf(wj, f6, a6); a7 = fmaf(wj, f7, a7);
    }
  }
  #pragma unroll
  for (int m = 1; m < 64; m <<= 1) {
    wacc.x += __shfl_xor(wacc.x, m);
    wacc.y += __shfl_xor(wacc.y, m);
    wacc.z += __shfl_xor(wacc.z, m);
    wacc.w += __shfl_xor(wacc.w, m);
  }
  float wsum = (hsel == 0) ? wacc.x : (hsel == 1) ? wacc.y : (hsel == 2) ? wacc.z : wacc.w;
  float inv = 1.f / (wsum + 1e-16f);
  float r0=a0*inv, r1=a1*inv, r2=a2*inv, r3=a3*inv;
  float r4=a4*inv, r5=a5*inv, r6=a6*inv, r7=a7*inv;
  #pragma unroll
  for (int m = 16; m <= 32; m <<= 1) {
    r0 += __shfl_xor(r0, m); r1 += __shfl_xor(r1, m);
    r2 += __shfl_xor(r2, m); r3 += __shfl_xor(r3, m);
    r4 += __shfl_xor(r4, m); r5 += __shfl_xor(r5, m);
    r6 += __shfl_xor(r6, m); r7 += __shfl_xor(r7, m);
  }
  if (lane < 16) {
    int dbase = lane * 8;
    const float4* gb = (const float4*)&gbias[dbase];
    float4 g0 = gb[0], g1 = gb[1];
    float4 o0 = make_float4(r0*0.25f + g0.x, r1*0.25f + g0.y, r2*0.25f + g0.z, r3*0.25f + g0.w);
    float4 o1 = make_float4(r4*0.25f + g1.x, r5*0.25f + g1.y, r6*0.25f + g1.z, r7*0.25f + g1.w);
    *(float4*)&hout[(size_t)n * DD + dbase] = o0;
    *(float4*)&hout[(size_t)n * DD + dbase + 4] = o1;
  }
}

// ---------------- batch norm ----------------
__global__ __launch_bounds__(128) void bn_stats(const float* __restrict__ h,
    float* __restrict__ bs, float* __restrict__ bq)
{
  int c = threadIdx.x;
  float s = 0.f, q = 0.f;
  for (int r = blockIdx.x; r < N_NODES; r += gridDim.x) {
    float v = h[(size_t)r * DD + c];
    s += v; q = fmaf(v, v, q);
  }
  atomicAdd(&bs[c], s);
  atomicAdd(&bq[c], q);
}

// reads fp32 hout, writes bf16 hbf (relu(bn(x))) — consumer (next GEMM / pool) is bf16
__global__ __launch_bounds__(256) void bn_apply(const float* __restrict__ h,
    const float* __restrict__ bs, const float* __restrict__ bq,
    const float* __restrict__ g, const float* __restrict__ b,
    unsigned short* __restrict__ hbf)
{
  const float invN = 1.f / (float)N_NODES;
  int i4 = blockIdx.x * 256 + threadIdx.x;
  int c0 = (i4 * 4) & (DD - 1);
  float4 v = *(const float4*)&h[(size_t)i4 * 4];
  float4 s = *(const float4*)&bs[c0];
  float4 q = *(const float4*)&bq[c0];
  float4 gg = *(const float4*)&g[c0];
  float4 bb = *(const float4*)&b[c0];
  float mu, var;
  ushort4 o;
  mu = s.x * invN; var = q.x * invN - mu * mu;
  o.x = f2bf(fmaxf((v.x - mu) * rsqrtf(var + EPS_BN) * gg.x + bb.x, 0.f));
  mu = s.y * invN; var = q.y * invN - mu * mu;
  o.y = f2bf(fmaxf((v.y - mu) * rsqrtf(var + EPS_BN) * gg.y + bb.y, 0.f));
  mu = s.z * invN; var = q.z * invN - mu * mu;
  o.z = f2bf(fmaxf((v.z - mu) * rsqrtf(var + EPS_BN) * gg.z + bb.z, 0.f));
  mu = s.w * invN; var = q.w * invN - mu * mu;
  o.w = f2bf(fmaxf((v.w - mu) * rsqrtf(var + EPS_BN) * gg.w + bb.w, 0.f));
  *(ushort4*)&hbf[(size_t)i4 * 4] = o;
}

// ---------------- global mean pool (batch sorted, bf16 input) ----------------
__global__ __launch_bounds__(256) void pool_kernel(const unsigned short* __restrict__ hbf,
    const int* __restrict__ batch, float* __restrict__ pooled)
{
  int g = blockIdx.x;
  int lo = 0, hi = N_NODES;
  while (lo < hi) { int mid = (lo + hi) >> 1; if (batch[mid] < g) lo = mid + 1; else hi = mid; }
  int start = lo;
  hi = N_NODES;
  while (lo < hi) { int mid = (lo + hi) >> 1; if (batch[mid] < g + 1) lo = mid + 1; else hi = mid; }
  int end = lo;
  int c = threadIdx.x & 127, ro = threadIdx.x >> 7;
  float s = 0.f;
  for (int r = start + ro; r < end; r += 2) s += bf2f(hbf[(size_t)r * DD + c]);
  __shared__ float red[256];
  red[threadIdx.x] = s;
  __syncthreads();
  if (ro == 0)
    pooled[g * DD + c] = (red[c] + red[128 + c]) / fmaxf((float)(end - start), 1.f);
}

// ---------------- MLP heads ----------------
__global__ __launch_bounds__(64) void heads_kernel(const float* __restrict__ pooled,
    const float* __restrict__ hw1, const float* __restrict__ hb1,
    const float* __restrict__ hw2, const float* __restrict__ hb2,
    float* __restrict__ out)
{
  int k = blockIdx.x >> 6;
  int g = blockIdx.x & 63;
  int o = threadIdx.x;
  const float4* p = (const float4*)&pooled[g * DD];
  const float4* w = (const float4*)&hw1[((size_t)k * 64 + o) * DD];
  float acc = hb1[k * 64 + o];
  #pragma unroll
  for (int d4 = 0; d4 < DD / 4; ++d4) {
    float4 pv = p[d4], wv = w[d4];
    acc += pv.x*wv.x + pv.y*wv.y + pv.z*wv.z + pv.w*wv.w;
  }
  float contrib = fmaxf(acc, 0.f) * hw2[k * 64 + o];
  #pragma unroll
  for (int m = 1; m < 64; m <<= 1) contrib += __shfl_xor(contrib, m);
  if (o == 0) out[g * 3 + k] = contrib + hb2[k];
}

extern "C" void kernel_launch(void* const* d_in, const int* in_sizes, int n_in,
                              void* d_out, int out_size, void* d_ws, size_t ws_size,
                              hipStream_t stream) {
  const float* x       = (const float*)d_in[0];
  const int*   ei      = (const int*)d_in[1];
  const int*   batch   = (const int*)d_in[2];
  const float* ip_w    = (const float*)d_in[3];
  const float* ip_b    = (const float*)d_in[4];
  const float* lin_w   = (const float*)d_in[5];
  const float* att_src = (const float*)d_in[6];
  const float* att_dst = (const float*)d_in[7];
  const float* gat_b   = (const float*)d_in[8];
  const float* bn_g    = (const float*)d_in[9];
  const float* bn_b    = (const float*)d_in[10];
  const float* hw1     = (const float*)d_in[11];
  const float* hb1     = (const float*)d_in[12];
  const float* hw2     = (const float*)d_in[13];
  const float* hb2     = (const float*)d_in[14];
  float* out = (float*)d_out;

  float* ws     = (float*)d_ws;
  float* hout   = ws;                              // [N,DD] fp32 (aggregate out)
  float* a_s    = hout + (size_t)N_NODES * DD;
  float* a_d    = a_s + (size_t)N_NODES * NH;
  float* bnsum  = a_d + (size_t)N_NODES * NH;      // NL*DD
  float* bnss   = bnsum + NL * DD;                 // NL*DD
  float* pooled = bnss + NL * DD;                  // NGRAPH*DD
  unsigned short* HPh   = (unsigned short*)(pooled + NGRAPH * DD);   // [N,HPD] bf16
  unsigned short* xbf   = HPh;                                       // alias: dead before HPh written
  unsigned short* hbf   = HPh + (size_t)N_NODES * HPD;               // [N,DD] bf16
  unsigned short* ipw_b = hbf + (size_t)N_NODES * DD;                // DD*DIN bf16
  unsigned short* linw_b= ipw_b + DD * DIN;                          // NL*HPD*DD bf16
  int*   hist   = (int*)(linw_b + (size_t)NL * HPD * DD);
  int*   offs   = hist + (N_NODES + 4);
  int*   cursor = offs + (N_NODES + 4);
  int*   esrc   = cursor + (N_NODES + 4);

  hipMemsetAsync(hist, 0, N_NODES * sizeof(int), stream);
  hipMemsetAsync(bnsum, 0, 2 * NL * DD * sizeof(float), stream);

  // weight + input conversions to bf16
  f2bf_kernel<<<(DD * DIN / 4 + 255) / 256, 256, 0, stream>>>(ip_w, ipw_b, DD * DIN / 4);
  f2bf_kernel<<<(NL * HPD * DD / 4 + 255) / 256, 256, 0, stream>>>(lin_w, linw_b, NL * HPD * DD / 4);
  f2bf_kernel<<<(N_NODES * DIN / 4 + 255) / 256, 256, 0, stream>>>(x, xbf, N_NODES * DIN / 4);

  hist_kernel<<<(ETOT + 255) / 256, 256, 0, stream>>>(ei, hist);
  scan_kernel<<<1, 1024, 0, stream>>>(hist, offs, cursor);
  scatter_kernel<<<(ETOT + 255) / 256, 256, 0, stream>>>(ei, cursor, esrc);

  const int MB = (N_NODES + 127) / 128;   // 157

  // input projection + relu -> hbf (bf16)
  gemm_mfma_nt<<<dim3(DD / 128, MB), 256, 0, stream>>>(
      xbf, ipw_b, hbf, N_NODES, DD, DIN, ip_b, 1);

  for (int l = 0; l < NL; ++l) {
    gemm_mfma_nt<<<dim3(HPD / 128, MB), 256, 0, stream>>>(
        hbf, linw_b + (size_t)l * HPD * DD, HPh, N_NODES, HPD, DD, nullptr, 0);
    attn_dots<<<N_NODES / 4, 256, 0, stream>>>(
        HPh, att_src + (size_t)l * HPD, att_dst + (size_t)l * HPD, a_s, a_d);
    aggregate<<<N_NODES / 4, 256, 0, stream>>>(
        HPh, a_s, a_d, offs, esrc, gat_b + (size_t)l * DD, hout);
    bn_stats<<<256, 128, 0, stream>>>(hout, bnsum + l * DD, bnss + l * DD);
    bn_apply<<<(N_NODES * DD / 4) / 256, 256, 0, stream>>>(
        hout, bnsum + l * DD, bnss + l * DD, bn_g + (size_t)l * DD, bn_b + (size_t)l * DD, hbf);
  }

  pool_kernel<<<NGRAPH, 256, 0, stream>>>(hbf, batch, pooled);
  heads_kernel<<<NL * NGRAPH, 64, 0, stream>>>(pooled, hw1, hb1, hw2, hb2, out);
}

// Round 8
// 514.471 us; speedup vs baseline: 1.5880x; 1.0177x over previous
//
#include <hip/hip_runtime.h>
#include <math.h>

#define N_NODES 20000
#define N_EDGES 320000
#define ETOT    (N_EDGES + N_NODES)
#define NGRAPH  64
#define DIN     256
#define DD      128
#define NH      4
#define NL      3
#define HPD     (NH*DD)   // 512
#define EPS_BN  1e-5f
#define SLOPE   0.2f

typedef __attribute__((ext_vector_type(8))) short short8;   // 8 bf16 (4 VGPRs)
typedef __attribute__((ext_vector_type(4))) float f32x4;    // MFMA acc

__device__ __forceinline__ float lrelu(float x) { return x >= 0.f ? x : SLOPE * x; }

__device__ __forceinline__ unsigned short f2bf(float f) {  // RTNE
  unsigned u = __float_as_uint(f);
  unsigned r = (u + 0x7FFFu + ((u >> 16) & 1u)) >> 16;
  return (unsigned short)r;
}
__device__ __forceinline__ float bf2f(unsigned short b) {
  return __uint_as_float((unsigned)b << 16);
}
__device__ __forceinline__ void bf2x(unsigned u, float& lo, float& hi) {
  lo = __uint_as_float(u << 16);
  hi = __uint_as_float(u & 0xFFFF0000u);
}

// ---------------- fp32 -> bf16 conversion (n divisible by 4) ----------------
__global__ void f2bf_kernel(const float* __restrict__ in, unsigned short* __restrict__ out, int n4) {
  int i = blockIdx.x * 256 + threadIdx.x;
  if (i >= n4) return;
  float4 v = *(const float4*)&in[(size_t)i * 4];
  ushort4 o;
  o.x = f2bf(v.x); o.y = f2bf(v.y); o.z = f2bf(v.z); o.w = f2bf(v.w);
  *(ushort4*)&out[(size_t)i * 4] = o;
}

// ---------------- CSR build ----------------
__global__ void hist_kernel(const int* __restrict__ ei, int* __restrict__ hist) {
  int idx = blockIdx.x * 256 + threadIdx.x;
  if (idx >= ETOT) return;
  int d = (idx < N_EDGES) ? ei[N_EDGES + idx] : (idx - N_EDGES);
  atomicAdd(&hist[d], 1);
}

__global__ __launch_bounds__(1024) void scan_kernel(const int* __restrict__ hist,
                                                    int* __restrict__ offs,
                                                    int* __restrict__ cursor) {
  __shared__ int wsum[16];
  int tid = threadIdx.x, lane = tid & 63, wid = tid >> 6;
  int carry = 0;
  for (int base = 0; base < N_NODES; base += 1024) {
    int i = base + tid;
    int x = (i < N_NODES) ? hist[i] : 0;
    int v = x;
    #pragma unroll
    for (int d = 1; d < 64; d <<= 1) {
      int t = __shfl_up(v, d);
      if (lane >= d) v += t;
    }
    if (lane == 63) wsum[wid] = v;
    __syncthreads();
    if (wid == 0) {
      int sv = (lane < 16) ? wsum[lane] : 0;
      #pragma unroll
      for (int d = 1; d < 16; d <<= 1) {
        int t = __shfl_up(sv, d);
        if (lane >= d) sv += t;
      }
      if (lane < 16) wsum[lane] = sv;
    }
    __syncthreads();
    int woff = (wid > 0) ? wsum[wid - 1] : 0;
    int incl = carry + woff + v;
    if (i < N_NODES) { int e = incl - x; offs[i] = e; cursor[i] = e; }
    carry += wsum[15];
    __syncthreads();
  }
  if (tid == 0) offs[N_NODES] = carry;
}

__global__ void scatter_kernel(const int* __restrict__ ei, int* __restrict__ cursor,
                               int* __restrict__ esrc) {
  int idx = blockIdx.x * 256 + threadIdx.x;
  if (idx >= ETOT) return;
  int s, d;
  if (idx < N_EDGES) { s = ei[idx]; d = ei[N_EDGES + idx]; }
  else { s = idx - N_EDGES; d = s; }
  int pos = atomicAdd(&cursor[d], 1);
  esrc[pos] = s;
}

// ---------------- MFMA bf16 GEMM NT: C[M,Nc] = act(A[M,K] @ B[Nc,K]^T + bias) ----
__global__ __launch_bounds__(256) void gemm_mfma_nt(
    const unsigned short* __restrict__ A,  // [M,K] bf16 row-major
    const unsigned short* __restrict__ B,  // [Nc,K] bf16 row-major
    unsigned short* __restrict__ Cb,       // [M,Nc] bf16 out
    int M, int Nc, int K,
    const float* __restrict__ bias, int do_relu)
{
  int lane = threadIdx.x & 63;
  int wid  = threadIdx.x >> 6;
  int wm = wid >> 1, wn = wid & 1;
  int m0 = blockIdx.y * 128 + wm * 64;
  int n0 = blockIdx.x * 128 + wn * 64;
  int lr = lane & 15;
  int kg = lane >> 4;      // k-group: k-offset kg*8

  f32x4 acc[4][4];
  #pragma unroll
  for (int i = 0; i < 4; ++i)
    #pragma unroll
    for (int j = 0; j < 4; ++j)
      acc[i][j] = (f32x4){0.f, 0.f, 0.f, 0.f};

  size_t abase[4], bbase[4];
  #pragma unroll
  for (int i = 0; i < 4; ++i) {
    int ar = m0 + i * 16 + lr;
    if (ar >= M) ar = M - 1;              // M-tail clamp (stores predicated)
    abase[i] = (size_t)ar * K;
    bbase[i] = (size_t)(n0 + i * 16 + lr) * K;
  }

  int nk = K >> 5;
  short8 afr[4], bfr[4], a2[4], b2[4];
  #pragma unroll
  for (int i = 0; i < 4; ++i) {
    afr[i] = *(const short8*)&A[abase[i] + kg * 8];
    bfr[i] = *(const short8*)&B[bbase[i] + kg * 8];
  }
  for (int ks = 0; ks < nk; ++ks) {
    if (ks + 1 < nk) {
      int ko = (ks + 1) * 32 + kg * 8;
      #pragma unroll
      for (int i = 0; i < 4; ++i) {
        a2[i] = *(const short8*)&A[abase[i] + ko];
        b2[i] = *(const short8*)&B[bbase[i] + ko];
      }
    }
    #pragma unroll
    for (int i = 0; i < 4; ++i)
      #pragma unroll
      for (int j = 0; j < 4; ++j)
        acc[i][j] = __builtin_amdgcn_mfma_f32_16x16x32_bf16(afr[i], bfr[j], acc[i][j], 0, 0, 0);
    if (ks + 1 < nk) {
      #pragma unroll
      for (int i = 0; i < 4; ++i) { afr[i] = a2[i]; bfr[i] = b2[i]; }
    }
  }

  float bz[4];
  #pragma unroll
  for (int j = 0; j < 4; ++j)
    bz[j] = bias ? bias[n0 + j * 16 + lr] : 0.f;
  #pragma unroll
  for (int i = 0; i < 4; ++i) {
    #pragma unroll
    for (int r = 0; r < 4; ++r) {
      int row = m0 + i * 16 + kg * 4 + r;
      if (row < M) {
        size_t rb = (size_t)row * Nc;
        #pragma unroll
        for (int j = 0; j < 4; ++j) {
          float v = acc[i][j][r] + bz[j];
          if (do_relu) v = fmaxf(v, 0.f);
          Cb[rb + n0 + j * 16 + lr] = f2bf(v);
        }
      }
    }
  }
}

// ---------------- attention dot products (bf16 h): a_src/a_dst [N,4] ----------------
__global__ __launch_bounds__(256) void attn_dots(const unsigned short* __restrict__ HPh,
    const float* __restrict__ atts, const float* __restrict__ attd,
    float* __restrict__ a_s, float* __restrict__ a_d)
{
  int lane = threadIdx.x & 63;
  int n = blockIdx.x * 4 + (threadIdx.x >> 6);
  uint4 u = *(const uint4*)&HPh[(size_t)n * HPD + lane * 8];
  float p0, p1, p2, p3, p4, p5, p6, p7;
  bf2x(u.x, p0, p1); bf2x(u.y, p2, p3); bf2x(u.z, p4, p5); bf2x(u.w, p6, p7);
  const float4* wsv = (const float4*)&atts[lane * 8];
  float4 s0 = wsv[0], s1 = wsv[1];
  const float4* wdv = (const float4*)&attd[lane * 8];
  float4 d0 = wdv[0], d1 = wdv[1];
  float ps = p0*s0.x + p1*s0.y + p2*s0.z + p3*s0.w
           + p4*s1.x + p5*s1.y + p6*s1.z + p7*s1.w;
  float pd = p0*d0.x + p1*d0.y + p2*d0.z + p3*d0.w
           + p4*d1.x + p5*d1.y + p6*d1.z + p7*d1.w;
  #pragma unroll
  for (int m = 1; m <= 8; m <<= 1) {
    ps += __shfl_xor(ps, m);
    pd += __shfl_xor(pd, m);
  }
  if ((lane & 15) == 0) {
    int h = lane >> 4;
    a_s[n * NH + h] = ps;
    a_d[n * NH + h] = pd;
  }
}

// ---------------- per-dst softmax + weighted aggregation + head-mean ----------------
// One wave per dst node. Weights computed as (16 edges x 4 heads) per 64 lanes;
// payload loop unrolled x4 with 4 independent 16B gathers in flight.
__global__ __launch_bounds__(256) void aggregate(const unsigned short* __restrict__ HPh,
    const float* __restrict__ a_s, const float* __restrict__ a_d,
    const int* __restrict__ offs, const int* __restrict__ esrc,
    const float* __restrict__ gbias, float* __restrict__ hout)
{
  int lane = threadIdx.x & 63;
  int n = blockIdx.x * 4 + (threadIdx.x >> 6);
  int start = offs[n], end = offs[n + 1];
  float4 ad4 = *(const float4*)&a_d[n * NH];
  int hsel = lane >> 4;
  int di = lane * 8;   // == hsel*128 + (lane&15)*8 : this lane's 8 dims of head hsel

  // phase 1: per-head max over incident edges (64 edges/pass, float4 a_s loads)
  float4 m4 = make_float4(-1e30f, -1e30f, -1e30f, -1e30f);
  for (int j = start + lane; j < end; j += 64) {
    int s = esrc[j];
    float4 as4 = *(const float4*)&a_s[s * NH];
    m4.x = fmaxf(m4.x, lrelu(as4.x + ad4.x));
    m4.y = fmaxf(m4.y, lrelu(as4.y + ad4.y));
    m4.z = fmaxf(m4.z, lrelu(as4.z + ad4.z));
    m4.w = fmaxf(m4.w, lrelu(as4.w + ad4.w));
  }
  #pragma unroll
  for (int m = 1; m < 64; m <<= 1) {
    m4.x = fmaxf(m4.x, __shfl_xor(m4.x, m));
    m4.y = fmaxf(m4.y, __shfl_xor(m4.y, m));
    m4.z = fmaxf(m4.z, __shfl_xor(m4.z, m));
    m4.w = fmaxf(m4.w, __shfl_xor(m4.w, m));
  }
  float mh = (lane & 32) ? ((lane & 16) ? m4.w : m4.z) : ((lane & 16) ? m4.y : m4.x);
  float ad = (lane & 32) ? ((lane & 16) ? ad4.w : ad4.z) : ((lane & 16) ? ad4.y : ad4.x);

  // phase 2: 16 edges x 4 heads per pass; lane (h*16+e) owns weight(edge e, head h)
  float wacc = 0.f;
  float a0=0,a1=0,a2=0,a3=0,a4=0,a5=0,a6=0,a7=0;
  int sl = lane & 48;
  for (int base = start; base < end; base += 16) {
    int e = lane & 15;
    int j = base + e;
    float w = 0.f; int s = 0;
    if (j < end) {
      s = esrc[j];
      float a = a_s[s * NH + hsel];
      w = __expf(lrelu(a + ad) - mh);
    }
    wacc += w;
    int cnt = min(16, end - base);
    int t = 0;
    for (; t + 3 < cnt; t += 4) {
      int s0 = __shfl(s, sl | t);
      int s1 = __shfl(s, sl | (t + 1));
      int s2 = __shfl(s, sl | (t + 2));
      int s3 = __shfl(s, sl | (t + 3));
      float w0 = __shfl(w, sl | t);
      float w1 = __shfl(w, sl | (t + 1));
      float w2 = __shfl(w, sl | (t + 2));
      float w3 = __shfl(w, sl | (t + 3));
      uint4 u0 = *(const uint4*)&HPh[(size_t)s0 * HPD + di];
      uint4 u1 = *(const uint4*)&HPh[(size_t)s1 * HPD + di];
      uint4 u2 = *(const uint4*)&HPh[(size_t)s2 * HPD + di];
      uint4 u3 = *(const uint4*)&HPh[(size_t)s3 * HPD + di];
      float f0, f1, f2, f3, f4, f5, f6, f7;
      bf2x(u0.x, f0, f1); bf2x(u0.y, f2, f3); bf2x(u0.z, f4, f5); bf2x(u0.w, f6, f7);
      a0 = fmaf(w0, f0, a0); a1 = fmaf(w0, f1, a1); a2 = fmaf(w0, f2, a2); a3 = fmaf(w0, f3, a3);
      a4 = fmaf(w0, f4, a4); a5 = fmaf(w0, f5, a5); a6 = fmaf(w0, f6, a6); a7 = fmaf(w0, f7, a7);
      bf2x(u1.x, f0, f1); bf2x(u1.y, f2, f3); bf2x(u1.z, f4, f5); bf2x(u1.w, f6, f7);
      a0 = fmaf(w1, f0, a0); a1 = fmaf(w1, f1, a1); a2 = fmaf(w1, f2, a2); a3 = fmaf(w1, f3, a3);
      a4 = fmaf(w1, f4, a4); a5 = fmaf(w1, f5, a5); a6 = fmaf(w1, f6, a6); a7 = fmaf(w1, f7, a7);
      bf2x(u2.x, f0, f1); bf2x(u2.y, f2, f3); bf2x(u2.z, f4, f5); bf2x(u2.w, f6, f7);
      a0 = fmaf(w2, f0, a0); a1 = fmaf(w2, f1, a1); a2 = fmaf(w2, f2, a2); a3 = fmaf(w2, f3, a3);
      a4 = fmaf(w2, f4, a4); a5 = fmaf(w2, f5, a5); a6 = fmaf(w2, f6, a6); a7 = fmaf(w2, f7, a7);
      bf2x(u3.x, f0, f1); bf2x(u3.y, f2, f3); bf2x(u3.z, f4, f5); bf2x(u3.w, f6, f7);
      a0 = fmaf(w3, f0, a0); a1 = fmaf(w3, f1, a1); a2 = fmaf(w3, f2, a2); a3 = fmaf(w3, f3, a3);
      a4 = fmaf(w3, f4, a4); a5 = fmaf(w3, f5, a5); a6 = fmaf(w3, f6, a6); a7 = fmaf(w3, f7, a7);
    }
    for (; t < cnt; ++t) {
      int sj = __shfl(s, sl | t);
      float wj = __shfl(w, sl | t);
      uint4 u = *(const uint4*)&HPh[(size_t)sj * HPD + di];
      float f0, f1, f2, f3, f4, f5, f6, f7;
      bf2x(u.x, f0, f1); bf2x(u.y, f2, f3); bf2x(u.z, f4, f5); bf2x(u.w, f6, f7);
      a0 = fmaf(wj, f0, a0); a1 = fmaf(wj, f1, a1); a2 = fmaf(wj, f2, a2); a3 = fmaf(wj, f3, a3);
      a4 = fmaf(wj, f4, a4); a5 = fmaf(wj, f5, a5); a6 = fmaf(wj, f6, a6); a7 = fmaf(wj, f7, a7);
    }
  }
  // wsum: reduce over the 16 e-lanes within this head group
  #pragma unroll
  for (int m = 1; m <= 8; m <<= 1) wacc += __shfl_xor(wacc, m);
  float inv = 1.f / (wacc + 1e-16f);
  float r0=a0*inv, r1=a1*inv, r2=a2*inv, r3=a3*inv;
  float r4=a4*inv, r5=a5*inv, r6=a6*inv, r7=a7*inv;
  // mean over heads: lanes l, l^16, l^32, l^48 hold the 4 heads of the same d-slice
  #pragma unroll
  for (int m = 16; m <= 32; m <<= 1) {
    r0 += __shfl_xor(r0, m); r1 += __shfl_xor(r1, m);
    r2 += __shfl_xor(r2, m); r3 += __shfl_xor(r3, m);
    r4 += __shfl_xor(r4, m); r5 += __shfl_xor(r5, m);
    r6 += __shfl_xor(r6, m); r7 += __shfl_xor(r7, m);
  }
  if (lane < 16) {
    int dbase = lane * 8;
    const float4* gb = (const float4*)&gbias[dbase];
    float4 g0 = gb[0], g1 = gb[1];
    float4 o0 = make_float4(r0*0.25f + g0.x, r1*0.25f + g0.y, r2*0.25f + g0.z, r3*0.25f + g0.w);
    float4 o1 = make_float4(r4*0.25f + g1.x, r5*0.25f + g1.y, r6*0.25f + g1.z, r7*0.25f + g1.w);
    *(float4*)&hout[(size_t)n * DD + dbase] = o0;
    *(float4*)&hout[(size_t)n * DD + dbase + 4] = o1;
  }
}

// ---------------- batch norm ----------------
__global__ __launch_bounds__(128) void bn_stats(const float* __restrict__ h,
    float* __restrict__ bs, float* __restrict__ bq)
{
  int c = threadIdx.x;
  float s = 0.f, q = 0.f;
  for (int r = blockIdx.x; r < N_NODES; r += gridDim.x) {
    float v = h[(size_t)r * DD + c];
    s += v; q = fmaf(v, v, q);
  }
  atomicAdd(&bs[c], s);
  atomicAdd(&bq[c], q);
}

// reads fp32 hout, writes bf16 hbf (relu(bn(x))) — consumer (next GEMM / pool) is bf16
__global__ __launch_bounds__(256) void bn_apply(const float* __restrict__ h,
    const float* __restrict__ bs, const float* __restrict__ bq,
    const float* __restrict__ g, const float* __restrict__ b,
    unsigned short* __restrict__ hbf)
{
  const float invN = 1.f / (float)N_NODES;
  int i4 = blockIdx.x * 256 + threadIdx.x;
  int c0 = (i4 * 4) & (DD - 1);
  float4 v = *(const float4*)&h[(size_t)i4 * 4];
  float4 s = *(const float4*)&bs[c0];
  float4 q = *(const float4*)&bq[c0];
  float4 gg = *(const float4*)&g[c0];
  float4 bb = *(const float4*)&b[c0];
  float mu, var;
  ushort4 o;
  mu = s.x * invN; var = q.x * invN - mu * mu;
  o.x = f2bf(fmaxf((v.x - mu) * rsqrtf(var + EPS_BN) * gg.x + bb.x, 0.f));
  mu = s.y * invN; var = q.y * invN - mu * mu;
  o.y = f2bf(fmaxf((v.y - mu) * rsqrtf(var + EPS_BN) * gg.y + bb.y, 0.f));
  mu = s.z * invN; var = q.z * invN - mu * mu;
  o.z = f2bf(fmaxf((v.z - mu) * rsqrtf(var + EPS_BN) * gg.z + bb.z, 0.f));
  mu = s.w * invN; var = q.w * invN - mu * mu;
  o.w = f2bf(fmaxf((v.w - mu) * rsqrtf(var + EPS_BN) * gg.w + bb.w, 0.f));
  *(ushort4*)&hbf[(size_t)i4 * 4] = o;
}

// ---------------- global mean pool (batch sorted, bf16 input) ----------------
__global__ __launch_bounds__(256) void pool_kernel(const unsigned short* __restrict__ hbf,
    const int* __restrict__ batch, float* __restrict__ pooled)
{
  int g = blockIdx.x;
  int lo = 0, hi = N_NODES;
  while (lo < hi) { int mid = (lo + hi) >> 1; if (batch[mid] < g) lo = mid + 1; else hi = mid; }
  int start = lo;
  hi = N_NODES;
  while (lo < hi) { int mid = (lo + hi) >> 1; if (batch[mid] < g + 1) lo = mid + 1; else hi = mid; }
  int end = lo;
  int c = threadIdx.x & 127, ro = threadIdx.x >> 7;
  float s = 0.f;
  for (int r = start + ro; r < end; r += 2) s += bf2f(hbf[(size_t)r * DD + c]);
  __shared__ float red[256];
  red[threadIdx.x] = s;
  __syncthreads();
  if (ro == 0)
    pooled[g * DD + c] = (red[c] + red[128 + c]) / fmaxf((float)(end - start), 1.f);
}

// ---------------- MLP heads ----------------
__global__ __launch_bounds__(64) void heads_kernel(const float* __restrict__ pooled,
    const float* __restrict__ hw1, const float* __restrict__ hb1,
    const float* __restrict__ hw2, const float* __restrict__ hb2,
    float* __restrict__ out)
{
  int k = blockIdx.x >> 6;
  int g = blockIdx.x & 63;
  int o = threadIdx.x;
  const float4* p = (const float4*)&pooled[g * DD];
  const float4* w = (const float4*)&hw1[((size_t)k * 64 + o) * DD];
  float acc = hb1[k * 64 + o];
  #pragma unroll
  for (int d4 = 0; d4 < DD / 4; ++d4) {
    float4 pv = p[d4], wv = w[d4];
    acc += pv.x*wv.x + pv.y*wv.y + pv.z*wv.z + pv.w*wv.w;
  }
  float contrib = fmaxf(acc, 0.f) * hw2[k * 64 + o];
  #pragma unroll
  for (int m = 1; m < 64; m <<= 1) contrib += __shfl_xor(contrib, m);
  if (o == 0) out[g * 3 + k] = contrib + hb2[k];
}

extern "C" void kernel_launch(void* const* d_in, const int* in_sizes, int n_in,
                              void* d_out, int out_size, void* d_ws, size_t ws_size,
                              hipStream_t stream) {
  const float* x       = (const float*)d_in[0];
  const int*   ei      = (const int*)d_in[1];
  const int*   batch   = (const int*)d_in[2];
  const float* ip_w    = (const float*)d_in[3];
  const float* ip_b    = (const float*)d_in[4];
  const float* lin_w   = (const float*)d_in[5];
  const float* att_src = (const float*)d_in[6];
  const float* att_dst = (const float*)d_in[7];
  const float* gat_b   = (const float*)d_in[8];
  const float* bn_g    = (const float*)d_in[9];
  const float* bn_b    = (const float*)d_in[10];
  const float* hw1     = (const float*)d_in[11];
  const float* hb1     = (const float*)d_in[12];
  const float* hw2     = (const float*)d_in[13];
  const float* hb2     = (const float*)d_in[14];
  float* out = (float*)d_out;

  float* ws     = (float*)d_ws;
  float* hout   = ws;                              // [N,DD] fp32 (aggregate out)
  float* a_s    = hout + (size_t)N_NODES * DD;
  float* a_d    = a_s + (size_t)N_NODES * NH;
  float* bnsum  = a_d + (size_t)N_NODES * NH;      // NL*DD
  float* bnss   = bnsum + NL * DD;                 // NL*DD
  float* pooled = bnss + NL * DD;                  // NGRAPH*DD
  unsigned short* HPh   = (unsigned short*)(pooled + NGRAPH * DD);   // [N,HPD] bf16
  unsigned short* xbf   = HPh;                                       // alias: dead before HPh written
  unsigned short* hbf   = HPh + (size_t)N_NODES * HPD;               // [N,DD] bf16
  unsigned short* ipw_b = hbf + (size_t)N_NODES * DD;                // DD*DIN bf16
  unsigned short* linw_b= ipw_b + DD * DIN;                          // NL*HPD*DD bf16
  int*   hist   = (int*)(linw_b + (size_t)NL * HPD * DD);
  int*   offs   = hist + (N_NODES + 4);
  int*   cursor = offs + (N_NODES + 4);
  int*   esrc   = cursor + (N_NODES + 4);

  hipMemsetAsync(hist, 0, N_NODES * sizeof(int), stream);
  hipMemsetAsync(bnsum, 0, 2 * NL * DD * sizeof(float), stream);

  // weight + input conversions to bf16
  f2bf_kernel<<<(DD * DIN / 4 + 255) / 256, 256, 0, stream>>>(ip_w, ipw_b, DD * DIN / 4);
  f2bf_kernel<<<(NL * HPD * DD / 4 + 255) / 256, 256, 0, stream>>>(lin_w, linw_b, NL * HPD * DD / 4);
  f2bf_kernel<<<(N_NODES * DIN / 4 + 255) / 256, 256, 0, stream>>>(x, xbf, N_NODES * DIN / 4);

  hist_kernel<<<(ETOT + 255) / 256, 256, 0, stream>>>(ei, hist);
  scan_kernel<<<1, 1024, 0, stream>>>(hist, offs, cursor);
  scatter_kernel<<<(ETOT + 255) / 256, 256, 0, stream>>>(ei, cursor, esrc);

  const int MB = (N_NODES + 127) / 128;   // 157

  // input projection + relu -> hbf (bf16)
  gemm_mfma_nt<<<dim3(DD / 128, MB), 256, 0, stream>>>(
      xbf, ipw_b, hbf, N_NODES, DD, DIN, ip_b, 1);

  for (int l = 0; l < NL; ++l) {
    gemm_mfma_nt<<<dim3(HPD / 128, MB), 256, 0, stream>>>(
        hbf, linw_b + (size_t)l * HPD * DD, HPh, N_NODES, HPD, DD, nullptr, 0);
    attn_dots<<<N_NODES / 4, 256, 0, stream>>>(
        HPh, att_src + (size_t)l * HPD, att_dst + (size_t)l * HPD, a_s, a_d);
    aggregate<<<N_NODES / 4, 256, 0, stream>>>(
        HPh, a_s, a_d, offs, esrc, gat_b + (size_t)l * DD, hout);
    bn_stats<<<256, 128, 0, stream>>>(hout, bnsum + l * DD, bnss + l * DD);
    bn_apply<<<(N_NODES * DD / 4) / 256, 256, 0, stream>>>(
        hout, bnsum + l * DD, bnss + l * DD, bn_g + (size_t)l * DD, bn_b + (size_t)l * DD, hbf);
  }

  pool_kernel<<<NGRAPH, 256, 0, stream>>>(hbf, batch, pooled);
  heads_kernel<<<NL * NGRAPH, 64, 0, stream>>>(pooled, hw1, hb1, hw2, hb2, out);
}

// Round 9
// 478.135 us; speedup vs baseline: 1.7086x; 1.0760x over previous
//
#include <hip/hip_runtime.h>
#include <math.h>

#define N_NODES 20000
#define N_EDGES 320000
#define ETOT    (N_EDGES + N_NODES)
#define NGRAPH  64
#define DIN     256
#define DD      128
#define NH      4
#define NL      3
#define HPD     (NH*DD)   // 512
#define EPS_BN  1e-5f
#define SLOPE   0.2f

typedef __attribute__((ext_vector_type(8))) short short8;   // 8 bf16 (4 VGPRs)
typedef __attribute__((ext_vector_type(4))) float f32x4;    // MFMA acc

__device__ __forceinline__ float lrelu(float x) { return x >= 0.f ? x : SLOPE * x; }

__device__ __forceinline__ unsigned short f2bf(float f) {  // RTNE
  unsigned u = __float_as_uint(f);
  unsigned r = (u + 0x7FFFu + ((u >> 16) & 1u)) >> 16;
  return (unsigned short)r;
}
__device__ __forceinline__ float bf2f(unsigned short b) {
  return __uint_as_float((unsigned)b << 16);
}
__device__ __forceinline__ void bf2x(unsigned u, float& lo, float& hi) {
  lo = __uint_as_float(u << 16);
  hi = __uint_as_float(u & 0xFFFF0000u);
}

// ---------------- fp32 -> bf16 conversion (n divisible by 4) ----------------
__global__ void f2bf_kernel(const float* __restrict__ in, unsigned short* __restrict__ out, int n4) {
  int i = blockIdx.x * 256 + threadIdx.x;
  if (i >= n4) return;
  float4 v = *(const float4*)&in[(size_t)i * 4];
  ushort4 o;
  o.x = f2bf(v.x); o.y = f2bf(v.y); o.z = f2bf(v.z); o.w = f2bf(v.w);
  *(ushort4*)&out[(size_t)i * 4] = o;
}

// ---------------- CSR build ----------------
__global__ void hist_kernel(const int* __restrict__ ei, int* __restrict__ hist) {
  int idx = blockIdx.x * 256 + threadIdx.x;
  if (idx >= ETOT) return;
  int d = (idx < N_EDGES) ? ei[N_EDGES + idx] : (idx - N_EDGES);
  atomicAdd(&hist[d], 1);
}

__global__ __launch_bounds__(1024) void scan_kernel(const int* __restrict__ hist,
                                                    int* __restrict__ offs,
                                                    int* __restrict__ cursor) {
  __shared__ int wsum[16];
  int tid = threadIdx.x, lane = tid & 63, wid = tid >> 6;
  int carry = 0;
  for (int base = 0; base < N_NODES; base += 1024) {
    int i = base + tid;
    int x = (i < N_NODES) ? hist[i] : 0;
    int v = x;
    #pragma unroll
    for (int d = 1; d < 64; d <<= 1) {
      int t = __shfl_up(v, d);
      if (lane >= d) v += t;
    }
    if (lane == 63) wsum[wid] = v;
    __syncthreads();
    if (wid == 0) {
      int sv = (lane < 16) ? wsum[lane] : 0;
      #pragma unroll
      for (int d = 1; d < 16; d <<= 1) {
        int t = __shfl_up(sv, d);
        if (lane >= d) sv += t;
      }
      if (lane < 16) wsum[lane] = sv;
    }
    __syncthreads();
    int woff = (wid > 0) ? wsum[wid - 1] : 0;
    int incl = carry + woff + v;
    if (i < N_NODES) { int e = incl - x; offs[i] = e; cursor[i] = e; }
    carry += wsum[15];
    __syncthreads();
  }
  if (tid == 0) offs[N_NODES] = carry;
}

__global__ void scatter_kernel(const int* __restrict__ ei, int* __restrict__ cursor,
                               int* __restrict__ esrc) {
  int idx = blockIdx.x * 256 + threadIdx.x;
  if (idx >= ETOT) return;
  int s, d;
  if (idx < N_EDGES) { s = ei[idx]; d = ei[N_EDGES + idx]; }
  else { s = idx - N_EDGES; d = s; }
  int pos = atomicAdd(&cursor[d], 1);
  esrc[pos] = s;
}

// ---------------- generic MFMA bf16 GEMM NT (used for input proj, K=256) ----------
__global__ __launch_bounds__(256) void gemm_mfma_nt(
    const unsigned short* __restrict__ A,  // [M,K] bf16 row-major
    const unsigned short* __restrict__ B,  // [Nc,K] bf16 row-major
    unsigned short* __restrict__ Cb,       // [M,Nc] bf16 out
    int M, int Nc, int K,
    const float* __restrict__ bias, int do_relu)
{
  int lane = threadIdx.x & 63;
  int wid  = threadIdx.x >> 6;
  int wm = wid >> 1, wn = wid & 1;
  int m0 = blockIdx.y * 128 + wm * 64;
  int n0 = blockIdx.x * 128 + wn * 64;
  int lr = lane & 15;
  int kg = lane >> 4;      // k-group: k-offset kg*8

  f32x4 acc[4][4];
  #pragma unroll
  for (int i = 0; i < 4; ++i)
    #pragma unroll
    for (int j = 0; j < 4; ++j)
      acc[i][j] = (f32x4){0.f, 0.f, 0.f, 0.f};

  size_t abase[4], bbase[4];
  #pragma unroll
  for (int i = 0; i < 4; ++i) {
    int ar = m0 + i * 16 + lr;
    if (ar >= M) ar = M - 1;              // M-tail clamp (stores predicated)
    abase[i] = (size_t)ar * K;
    bbase[i] = (size_t)(n0 + i * 16 + lr) * K;
  }

  int nk = K >> 5;
  short8 afr[4], bfr[4], a2[4], b2[4];
  #pragma unroll
  for (int i = 0; i < 4; ++i) {
    afr[i] = *(const short8*)&A[abase[i] + kg * 8];
    bfr[i] = *(const short8*)&B[bbase[i] + kg * 8];
  }
  for (int ks = 0; ks < nk; ++ks) {
    if (ks + 1 < nk) {
      int ko = (ks + 1) * 32 + kg * 8;
      #pragma unroll
      for (int i = 0; i < 4; ++i) {
        a2[i] = *(const short8*)&A[abase[i] + ko];
        b2[i] = *(const short8*)&B[bbase[i] + ko];
      }
    }
    #pragma unroll
    for (int i = 0; i < 4; ++i)
      #pragma unroll
      for (int j = 0; j < 4; ++j)
        acc[i][j] = __builtin_amdgcn_mfma_f32_16x16x32_bf16(afr[i], bfr[j], acc[i][j], 0, 0, 0);
    if (ks + 1 < nk) {
      #pragma unroll
      for (int i = 0; i < 4; ++i) { afr[i] = a2[i]; bfr[i] = b2[i]; }
    }
  }

  float bz[4];
  #pragma unroll
  for (int j = 0; j < 4; ++j)
    bz[j] = bias ? bias[n0 + j * 16 + lr] : 0.f;
  #pragma unroll
  for (int i = 0; i < 4; ++i) {
    #pragma unroll
    for (int r = 0; r < 4; ++r) {
      int row = m0 + i * 16 + kg * 4 + r;
      if (row < M) {
        size_t rb = (size_t)row * Nc;
        #pragma unroll
        for (int j = 0; j < 4; ++j) {
          float v = acc[i][j][r] + bz[j];
          if (do_relu) v = fmaxf(v, 0.f);
          Cb[rb + n0 + j * 16 + lr] = f2bf(v);
        }
      }
    }
  }
}

// ---------------- K=128 specialized MFMA GEMM: all fragments prefetched ----------
// One latency exposure (32 loads up-front), then 64 back-to-back MFMAs.
// No bias / no relu (layer projections). Nc % 128 == 0.
__global__ __launch_bounds__(256) void gemm_mfma_k128(
    const unsigned short* __restrict__ A,  // [M,128] bf16
    const unsigned short* __restrict__ B,  // [Nc,128] bf16
    unsigned short* __restrict__ Cb,       // [M,Nc] bf16 out
    int M, int Nc)
{
  int lane = threadIdx.x & 63;
  int wid  = threadIdx.x >> 6;
  int wm = wid >> 1, wn = wid & 1;
  int m0 = blockIdx.y * 128 + wm * 64;
  int n0 = blockIdx.x * 128 + wn * 64;
  int lr = lane & 15;
  int kg = lane >> 4;

  const unsigned short* Ap[4];
  const unsigned short* Bp[4];
  #pragma unroll
  for (int i = 0; i < 4; ++i) {
    int ar = m0 + i * 16 + lr;
    if (ar >= M) ar = M - 1;              // M-tail clamp (stores predicated)
    Ap[i] = A + (size_t)ar * 128 + kg * 8;
    Bp[i] = B + (size_t)(n0 + i * 16 + lr) * 128 + kg * 8;
  }

  short8 a[4][4], b[4][4];                // [ks][frag] — all static indices
  #pragma unroll
  for (int ks = 0; ks < 4; ++ks)
    #pragma unroll
    for (int i = 0; i < 4; ++i) {
      a[ks][i] = *(const short8*)(Ap[i] + ks * 32);
      b[ks][i] = *(const short8*)(Bp[i] + ks * 32);
    }

  f32x4 acc[4][4];
  #pragma unroll
  for (int i = 0; i < 4; ++i)
    #pragma unroll
    for (int j = 0; j < 4; ++j)
      acc[i][j] = (f32x4){0.f, 0.f, 0.f, 0.f};

  #pragma unroll
  for (int ks = 0; ks < 4; ++ks)
    #pragma unroll
    for (int i = 0; i < 4; ++i)
      #pragma unroll
      for (int j = 0; j < 4; ++j)
        acc[i][j] = __builtin_amdgcn_mfma_f32_16x16x32_bf16(a[ks][i], b[ks][j], acc[i][j], 0, 0, 0);

  #pragma unroll
  for (int i = 0; i < 4; ++i) {
    #pragma unroll
    for (int r = 0; r < 4; ++r) {
      int row = m0 + i * 16 + kg * 4 + r;
      if (row < M) {
        size_t rb = (size_t)row * Nc;
        #pragma unroll
        for (int j = 0; j < 4; ++j)
          Cb[rb + n0 + j * 16 + lr] = f2bf(acc[i][j][r]);
      }
    }
  }
}

// ---------------- attention dot products (bf16 h): a_src/a_dst [N,4] ----------------
__global__ __launch_bounds__(256) void attn_dots(const unsigned short* __restrict__ HPh,
    const float* __restrict__ atts, const float* __restrict__ attd,
    float* __restrict__ a_s, float* __restrict__ a_d)
{
  int lane = threadIdx.x & 63;
  int n = blockIdx.x * 4 + (threadIdx.x >> 6);
  uint4 u = *(const uint4*)&HPh[(size_t)n * HPD + lane * 8];
  float p0, p1, p2, p3, p4, p5, p6, p7;
  bf2x(u.x, p0, p1); bf2x(u.y, p2, p3); bf2x(u.z, p4, p5); bf2x(u.w, p6, p7);
  const float4* wsv = (const float4*)&atts[lane * 8];
  float4 s0 = wsv[0], s1 = wsv[1];
  const float4* wdv = (const float4*)&attd[lane * 8];
  float4 d0 = wdv[0], d1 = wdv[1];
  float ps = p0*s0.x + p1*s0.y + p2*s0.z + p3*s0.w
           + p4*s1.x + p5*s1.y + p6*s1.z + p7*s1.w;
  float pd = p0*d0.x + p1*d0.y + p2*d0.z + p3*d0.w
           + p4*d1.x + p5*d1.y + p6*d1.z + p7*d1.w;
  #pragma unroll
  for (int m = 1; m <= 8; m <<= 1) {
    ps += __shfl_xor(ps, m);
    pd += __shfl_xor(pd, m);
  }
  if ((lane & 15) == 0) {
    int h = lane >> 4;
    a_s[n * NH + h] = ps;
    a_d[n * NH + h] = pd;
  }
}

// ---------------- per-dst softmax + weighted aggregation + head-mean ----------------
__global__ __launch_bounds__(256) void aggregate(const unsigned short* __restrict__ HPh,
    const float* __restrict__ a_s, const float* __restrict__ a_d,
    const int* __restrict__ offs, const int* __restrict__ esrc,
    const float* __restrict__ gbias, float* __restrict__ hout)
{
  int lane = threadIdx.x & 63;
  int n = blockIdx.x * 4 + (threadIdx.x >> 6);
  int start = offs[n], end = offs[n + 1];
  float4 ad4 = *(const float4*)&a_d[n * NH];
  int hsel = lane >> 4;
  int di = lane * 8;   // == hsel*128 + (lane&15)*8

  float4 m4 = make_float4(-1e30f, -1e30f, -1e30f, -1e30f);
  for (int j = start + lane; j < end; j += 64) {
    int s = esrc[j];
    float4 as4 = *(const float4*)&a_s[s * NH];
    m4.x = fmaxf(m4.x, lrelu(as4.x + ad4.x));
    m4.y = fmaxf(m4.y, lrelu(as4.y + ad4.y));
    m4.z = fmaxf(m4.z, lrelu(as4.z + ad4.z));
    m4.w = fmaxf(m4.w, lrelu(as4.w + ad4.w));
  }
  #pragma unroll
  for (int m = 1; m < 64; m <<= 1) {
    m4.x = fmaxf(m4.x, __shfl_xor(m4.x, m));
    m4.y = fmaxf(m4.y, __shfl_xor(m4.y, m));
    m4.z = fmaxf(m4.z, __shfl_xor(m4.z, m));
    m4.w = fmaxf(m4.w, __shfl_xor(m4.w, m));
  }
  float mh = (lane & 32) ? ((lane & 16) ? m4.w : m4.z) : ((lane & 16) ? m4.y : m4.x);
  float ad = (lane & 32) ? ((lane & 16) ? ad4.w : ad4.z) : ((lane & 16) ? ad4.y : ad4.x);

  float wacc = 0.f;
  float a0=0,a1=0,a2=0,a3=0,a4=0,a5=0,a6=0,a7=0;
  int sl = lane & 48;
  for (int base = start; base < end; base += 16) {
    int e = lane & 15;
    int j = base + e;
    float w = 0.f; int s = 0;
    if (j < end) {
      s = esrc[j];
      float a = a_s[s * NH + hsel];
      w = __expf(lrelu(a + ad) - mh);
    }
    wacc += w;
    int cnt = min(16, end - base);
    int t = 0;
    for (; t + 3 < cnt; t += 4) {
      int s0 = __shfl(s, sl | t);
      int s1 = __shfl(s, sl | (t + 1));
      int s2 = __shfl(s, sl | (t + 2));
      int s3 = __shfl(s, sl | (t + 3));
      float w0 = __shfl(w, sl | t);
      float w1 = __shfl(w, sl | (t + 1));
      float w2 = __shfl(w, sl | (t + 2));
      float w3 = __shfl(w, sl | (t + 3));
      uint4 u0 = *(const uint4*)&HPh[(size_t)s0 * HPD + di];
      uint4 u1 = *(const uint4*)&HPh[(size_t)s1 * HPD + di];
      uint4 u2 = *(const uint4*)&HPh[(size_t)s2 * HPD + di];
      uint4 u3 = *(const uint4*)&HPh[(size_t)s3 * HPD + di];
      float f0, f1, f2, f3, f4, f5, f6, f7;
      bf2x(u0.x, f0, f1); bf2x(u0.y, f2, f3); bf2x(u0.z, f4, f5); bf2x(u0.w, f6, f7);
      a0 = fmaf(w0, f0, a0); a1 = fmaf(w0, f1, a1); a2 = fmaf(w0, f2, a2); a3 = fmaf(w0, f3, a3);
      a4 = fmaf(w0, f4, a4); a5 = fmaf(w0, f5, a5); a6 = fmaf(w0, f6, a6); a7 = fmaf(w0, f7, a7);
      bf2x(u1.x, f0, f1); bf2x(u1.y, f2, f3); bf2x(u1.z, f4, f5); bf2x(u1.w, f6, f7);
      a0 = fmaf(w1, f0, a0); a1 = fmaf(w1, f1, a1); a2 = fmaf(w1, f2, a2); a3 = fmaf(w1, f3, a3);
      a4 = fmaf(w1, f4, a4); a5 = fmaf(w1, f5, a5); a6 = fmaf(w1, f6, a6); a7 = fmaf(w1, f7, a7);
      bf2x(u2.x, f0, f1); bf2x(u2.y, f2, f3); bf2x(u2.z, f4, f5); bf2x(u2.w, f6, f7);
      a0 = fmaf(w2, f0, a0); a1 = fmaf(w2, f1, a1); a2 = fmaf(w2, f2, a2); a3 = fmaf(w2, f3, a3);
      a4 = fmaf(w2, f4, a4); a5 = fmaf(w2, f5, a5); a6 = fmaf(w2, f6, a6); a7 = fmaf(w2, f7, a7);
      bf2x(u3.x, f0, f1); bf2x(u3.y, f2, f3); bf2x(u3.z, f4, f5); bf2x(u3.w, f6, f7);
      a0 = fmaf(w3, f0, a0); a1 = fmaf(w3, f1, a1); a2 = fmaf(w3, f2, a2); a3 = fmaf(w3, f3, a3);
      a4 = fmaf(w3, f4, a4); a5 = fmaf(w3, f5, a5); a6 = fmaf(w3, f6, a6); a7 = fmaf(w3, f7, a7);
    }
    for (; t < cnt; ++t) {
      int sj = __shfl(s, sl | t);
      float wj = __shfl(w, sl | t);
      uint4 u = *(const uint4*)&HPh[(size_t)sj * HPD + di];
      float f0, f1, f2, f3, f4, f5, f6, f7;
      bf2x(u.x, f0, f1); bf2x(u.y, f2, f3); bf2x(u.z, f4, f5); bf2x(u.w, f6, f7);
      a0 = fmaf(wj, f0, a0); a1 = fmaf(wj, f1, a1); a2 = fmaf(wj, f2, a2); a3 = fmaf(wj, f3, a3);
      a4 = fmaf(wj, f4, a4); a5 = fmaf(wj, f5, a5); a6 = fmaf(wj, f6, a6); a7 = fmaf(wj, f7, a7);
    }
  }
  #pragma unroll
  for (int m = 1; m <= 8; m <<= 1) wacc += __shfl_xor(wacc, m);
  float inv = 1.f / (wacc + 1e-16f);
  float r0=a0*inv, r1=a1*inv, r2=a2*inv, r3=a3*inv;
  float r4=a4*inv, r5=a5*inv, r6=a6*inv, r7=a7*inv;
  #pragma unroll
  for (int m = 16; m <= 32; m <<= 1) {
    r0 += __shfl_xor(r0, m); r1 += __shfl_xor(r1, m);
    r2 += __shfl_xor(r2, m); r3 += __shfl_xor(r3, m);
    r4 += __shfl_xor(r4, m); r5 += __shfl_xor(r5, m);
    r6 += __shfl_xor(r6, m); r7 += __shfl_xor(r7, m);
  }
  if (lane < 16) {
    int dbase = lane * 8;
    const float4* gb = (const float4*)&gbias[dbase];
    float4 g0 = gb[0], g1 = gb[1];
    float4 o0 = make_float4(r0*0.25f + g0.x, r1*0.25f + g0.y, r2*0.25f + g0.z, r3*0.25f + g0.w);
    float4 o1 = make_float4(r4*0.25f + g1.x, r5*0.25f + g1.y, r6*0.25f + g1.z, r7*0.25f + g1.w);
    *(float4*)&hout[(size_t)n * DD + dbase] = o0;
    *(float4*)&hout[(size_t)n * DD + dbase + 4] = o1;
  }
}

// ---------------- batch norm ----------------
__global__ __launch_bounds__(128) void bn_stats(const float* __restrict__ h,
    float* __restrict__ bs, float* __restrict__ bq)
{
  int c = threadIdx.x;
  float s = 0.f, q = 0.f;
  for (int r = blockIdx.x; r < N_NODES; r += gridDim.x) {
    float v = h[(size_t)r * DD + c];
    s += v; q = fmaf(v, v, q);
  }
  atomicAdd(&bs[c], s);
  atomicAdd(&bq[c], q);
}

__global__ __launch_bounds__(256) void bn_apply(const float* __restrict__ h,
    const float* __restrict__ bs, const float* __restrict__ bq,
    const float* __restrict__ g, const float* __restrict__ b,
    unsigned short* __restrict__ hbf)
{
  const float invN = 1.f / (float)N_NODES;
  int i4 = blockIdx.x * 256 + threadIdx.x;
  int c0 = (i4 * 4) & (DD - 1);
  float4 v = *(const float4*)&h[(size_t)i4 * 4];
  float4 s = *(const float4*)&bs[c0];
  float4 q = *(const float4*)&bq[c0];
  float4 gg = *(const float4*)&g[c0];
  float4 bb = *(const float4*)&b[c0];
  float mu, var;
  ushort4 o;
  mu = s.x * invN; var = q.x * invN - mu * mu;
  o.x = f2bf(fmaxf((v.x - mu) * rsqrtf(var + EPS_BN) * gg.x + bb.x, 0.f));
  mu = s.y * invN; var = q.y * invN - mu * mu;
  o.y = f2bf(fmaxf((v.y - mu) * rsqrtf(var + EPS_BN) * gg.y + bb.y, 0.f));
  mu = s.z * invN; var = q.z * invN - mu * mu;
  o.z = f2bf(fmaxf((v.z - mu) * rsqrtf(var + EPS_BN) * gg.z + bb.z, 0.f));
  mu = s.w * invN; var = q.w * invN - mu * mu;
  o.w = f2bf(fmaxf((v.w - mu) * rsqrtf(var + EPS_BN) * gg.w + bb.w, 0.f));
  *(ushort4*)&hbf[(size_t)i4 * 4] = o;
}

// ---------------- global mean pool: parallel partial sums ----------------
// 8 blocks per graph; fp32 atomicAdd partials into zeroed psum (16 adds/address).
__global__ __launch_bounds__(256) void pool_partial(const unsigned short* __restrict__ hbf,
    const int* __restrict__ batch, float* __restrict__ psum)
{
  int g = blockIdx.x >> 3, sl = blockIdx.x & 7;
  int lo = 0, hi = N_NODES;
  while (lo < hi) { int mid = (lo + hi) >> 1; if (batch[mid] < g) lo = mid + 1; else hi = mid; }
  int start = lo;
  hi = N_NODES;
  while (lo < hi) { int mid = (lo + hi) >> 1; if (batch[mid] < g + 1) lo = mid + 1; else hi = mid; }
  int end = lo;
  int c = threadIdx.x & 127, ro = threadIdx.x >> 7;  // 16 row-streams per graph
  float s = 0.f;
  for (int r = start + sl * 2 + ro; r < end; r += 16) s += bf2f(hbf[(size_t)r * DD + c]);
  if (s != 0.f || true) atomicAdd(&psum[g * DD + c], s);
}

// ---------------- MLP heads (divides pooled sums by count) ----------------
__global__ __launch_bounds__(64) void heads_kernel(const float* __restrict__ psum,
    const int* __restrict__ batch,
    const float* __restrict__ hw1, const float* __restrict__ hb1,
    const float* __restrict__ hw2, const float* __restrict__ hb2,
    float* __restrict__ out)
{
  int k = blockIdx.x >> 6;
  int g = blockIdx.x & 63;
  int o = threadIdx.x;
  int lo = 0, hi = N_NODES;
  while (lo < hi) { int mid = (lo + hi) >> 1; if (batch[mid] < g) lo = mid + 1; else hi = mid; }
  int start = lo;
  hi = N_NODES;
  while (lo < hi) { int mid = (lo + hi) >> 1; if (batch[mid] < g + 1) lo = mid + 1; else hi = mid; }
  float inv = 1.f / fmaxf((float)(lo - start), 1.f);
  const float4* p = (const float4*)&psum[g * DD];
  const float4* w = (const float4*)&hw1[((size_t)k * 64 + o) * DD];
  float dot = 0.f;
  #pragma unroll
  for (int d4 = 0; d4 < DD / 4; ++d4) {
    float4 pv = p[d4], wv = w[d4];
    dot += pv.x*wv.x + pv.y*wv.y + pv.z*wv.z + pv.w*wv.w;
  }
  float acc = fmaf(dot, inv, hb1[k * 64 + o]);
  float contrib = fmaxf(acc, 0.f) * hw2[k * 64 + o];
  #pragma unroll
  for (int m = 1; m < 64; m <<= 1) contrib += __shfl_xor(contrib, m);
  if (o == 0) out[g * 3 + k] = contrib + hb2[k];
}

extern "C" void kernel_launch(void* const* d_in, const int* in_sizes, int n_in,
                              void* d_out, int out_size, void* d_ws, size_t ws_size,
                              hipStream_t stream) {
  const float* x       = (const float*)d_in[0];
  const int*   ei      = (const int*)d_in[1];
  const int*   batch   = (const int*)d_in[2];
  const float* ip_w    = (const float*)d_in[3];
  const float* ip_b    = (const float*)d_in[4];
  const float* lin_w   = (const float*)d_in[5];
  const float* att_src = (const float*)d_in[6];
  const float* att_dst = (const float*)d_in[7];
  const float* gat_b   = (const float*)d_in[8];
  const float* bn_g    = (const float*)d_in[9];
  const float* bn_b    = (const float*)d_in[10];
  const float* hw1     = (const float*)d_in[11];
  const float* hb1     = (const float*)d_in[12];
  const float* hw2     = (const float*)d_in[13];
  const float* hb2     = (const float*)d_in[14];
  float* out = (float*)d_out;

  float* ws     = (float*)d_ws;
  float* hout   = ws;                              // [N,DD] fp32 (aggregate out)
  float* a_s    = hout + (size_t)N_NODES * DD;
  float* a_d    = a_s + (size_t)N_NODES * NH;
  float* bnsum  = a_d + (size_t)N_NODES * NH;      // NL*DD
  float* bnss   = bnsum + NL * DD;                 // NL*DD
  float* pooled = bnss + NL * DD;                  // NGRAPH*DD (psum)
  unsigned short* HPh   = (unsigned short*)(pooled + NGRAPH * DD);   // [N,HPD] bf16
  unsigned short* xbf   = HPh;                                       // alias: dead before HPh written
  unsigned short* hbf   = HPh + (size_t)N_NODES * HPD;               // [N,DD] bf16
  unsigned short* ipw_b = hbf + (size_t)N_NODES * DD;                // DD*DIN bf16
  unsigned short* linw_b= ipw_b + DD * DIN;                          // NL*HPD*DD bf16
  int*   hist   = (int*)(linw_b + (size_t)NL * HPD * DD);
  int*   offs   = hist + (N_NODES + 4);
  int*   cursor = offs + (N_NODES + 4);
  int*   esrc   = cursor + (N_NODES + 4);

  hipMemsetAsync(hist, 0, N_NODES * sizeof(int), stream);
  hipMemsetAsync(bnsum, 0, 2 * NL * DD * sizeof(float), stream);
  hipMemsetAsync(pooled, 0, NGRAPH * DD * sizeof(float), stream);

  // weight + input conversions to bf16
  f2bf_kernel<<<(DD * DIN / 4 + 255) / 256, 256, 0, stream>>>(ip_w, ipw_b, DD * DIN / 4);
  f2bf_kernel<<<(NL * HPD * DD / 4 + 255) / 256, 256, 0, stream>>>(lin_w, linw_b, NL * HPD * DD / 4);
  f2bf_kernel<<<(N_NODES * DIN / 4 + 255) / 256, 256, 0, stream>>>(x, xbf, N_NODES * DIN / 4);

  hist_kernel<<<(ETOT + 255) / 256, 256, 0, stream>>>(ei, hist);
  scan_kernel<<<1, 1024, 0, stream>>>(hist, offs, cursor);
  scatter_kernel<<<(ETOT + 255) / 256, 256, 0, stream>>>(ei, cursor, esrc);

  const int MB = (N_NODES + 127) / 128;   // 157

  // input projection + relu -> hbf (bf16)
  gemm_mfma_nt<<<dim3(DD / 128, MB), 256, 0, stream>>>(
      xbf, ipw_b, hbf, N_NODES, DD, DIN, ip_b, 1);

  for (int l = 0; l < NL; ++l) {
    gemm_mfma_k128<<<dim3(HPD / 128, MB), 256, 0, stream>>>(
        hbf, linw_b + (size_t)l * HPD * DD, HPh, N_NODES, HPD);
    attn_dots<<<N_NODES / 4, 256, 0, stream>>>(
        HPh, att_src + (size_t)l * HPD, att_dst + (size_t)l * HPD, a_s, a_d);
    aggregate<<<N_NODES / 4, 256, 0, stream>>>(
        HPh, a_s, a_d, offs, esrc, gat_b + (size_t)l * DD, hout);
    bn_stats<<<256, 128, 0, stream>>>(hout, bnsum + l * DD, bnss + l * DD);
    bn_apply<<<(N_NODES * DD / 4) / 256, 256, 0, stream>>>(
        hout, bnsum + l * DD, bnss + l * DD, bn_g + (size_t)l * DD, bn_b + (size_t)l * DD, hbf);
  }

  pool_partial<<<NGRAPH * 8, 256, 0, stream>>>(hbf, batch, pooled);
  heads_kernel<<<NL * NGRAPH, 64, 0, stream>>>(pooled, batch, hw1, hb1, hw2, hb2, out);
}

// Round 10
// 443.356 us; speedup vs baseline: 1.8427x; 1.0784x over previous
//
#include <hip/hip_runtime.h>
#include <math.h>

#define N_NODES 20000
#define N_EDGES 320000
#define ETOT    (N_EDGES + N_NODES)
#define NGRAPH  64
#define DIN     256
#define DD      128
#define NH      4
#define NL      3
#define HPD     (NH*DD)   // 512
#define EPS_BN  1e-5f
#define SLOPE   0.2f
#define SCAN_NB ((N_NODES + 1023) / 1024)   // 20

typedef __attribute__((ext_vector_type(8))) short short8;   // 8 bf16 (4 VGPRs)
typedef __attribute__((ext_vector_type(4))) float f32x4;    // MFMA acc

__device__ __forceinline__ float lrelu(float x) { return x >= 0.f ? x : SLOPE * x; }

__device__ __forceinline__ unsigned short f2bf(float f) {  // RTNE
  unsigned u = __float_as_uint(f);
  unsigned r = (u + 0x7FFFu + ((u >> 16) & 1u)) >> 16;
  return (unsigned short)r;
}
__device__ __forceinline__ float bf2f(unsigned short b) {
  return __uint_as_float((unsigned)b << 16);
}
__device__ __forceinline__ void bf2x(unsigned u, float& lo, float& hi) {
  lo = __uint_as_float(u << 16);
  hi = __uint_as_float(u & 0xFFFF0000u);
}
__device__ __forceinline__ short8 pack8(float4 a, float4 b) {
  short8 r;
  r[0] = (short)f2bf(a.x); r[1] = (short)f2bf(a.y);
  r[2] = (short)f2bf(a.z); r[3] = (short)f2bf(a.w);
  r[4] = (short)f2bf(b.x); r[5] = (short)f2bf(b.y);
  r[6] = (short)f2bf(b.z); r[7] = (short)f2bf(b.w);
  return r;
}

// ---------------- fp32 -> bf16 conversion (n divisible by 4) ----------------
__global__ void f2bf_kernel(const float* __restrict__ in, unsigned short* __restrict__ out, int n4) {
  int i = blockIdx.x * 256 + threadIdx.x;
  if (i >= n4) return;
  float4 v = *(const float4*)&in[(size_t)i * 4];
  ushort4 o;
  o.x = f2bf(v.x); o.y = f2bf(v.y); o.z = f2bf(v.z); o.w = f2bf(v.w);
  *(ushort4*)&out[(size_t)i * 4] = o;
}

// ---------------- CSR build ----------------
__global__ void hist_kernel(const int* __restrict__ ei, int* __restrict__ hist) {
  int idx = blockIdx.x * 256 + threadIdx.x;
  if (idx >= ETOT) return;
  int d = (idx < N_EDGES) ? ei[N_EDGES + idx] : (idx - N_EDGES);
  atomicAdd(&hist[d], 1);
}

// parallel 3-phase scan: per-block local exclusive scan + block sums
__global__ __launch_bounds__(1024) void scan_blk(const int* __restrict__ hist,
                                                 int* __restrict__ offs,
                                                 int* __restrict__ bsum) {
  __shared__ int wsum[16];
  int tid = threadIdx.x, lane = tid & 63, wid = tid >> 6;
  int i = blockIdx.x * 1024 + tid;
  int x = (i < N_NODES) ? hist[i] : 0;
  int v = x;
  #pragma unroll
  for (int d = 1; d < 64; d <<= 1) {
    int t = __shfl_up(v, d);
    if (lane >= d) v += t;
  }
  if (lane == 63) wsum[wid] = v;
  __syncthreads();
  if (wid == 0) {
    int sv = (lane < 16) ? wsum[lane] : 0;
    #pragma unroll
    for (int d = 1; d < 16; d <<= 1) {
      int t = __shfl_up(sv, d);
      if (lane >= d) sv += t;
    }
    if (lane < 16) wsum[lane] = sv;
  }
  __syncthreads();
  int woff = (wid > 0) ? wsum[wid - 1] : 0;
  int incl = woff + v;
  if (i < N_NODES) offs[i] = incl - x;          // local exclusive
  if (tid == 1023) bsum[blockIdx.x] = incl;     // block total
}

__global__ void scan_top(int* __restrict__ bsum, int* __restrict__ offs) {
  int lane = threadIdx.x;   // 64 threads, 1 block
  int v = (lane < SCAN_NB) ? bsum[lane] : 0;
  int incl = v;
  #pragma unroll
  for (int d = 1; d < 64; d <<= 1) {
    int t = __shfl_up(incl, d);
    if (lane >= d) incl += t;
  }
  if (lane < SCAN_NB) bsum[lane] = incl - v;    // exclusive base per block
  if (lane == 63) offs[N_NODES] = incl;         // grand total (== ETOT)
}

__global__ void scan_fix(const int* __restrict__ bsum, int* __restrict__ offs,
                         int* __restrict__ cursor) {
  int i = blockIdx.x * 256 + threadIdx.x;
  if (i >= N_NODES) return;
  int v = offs[i] + bsum[i >> 10];
  offs[i] = v;
  cursor[i] = v;
}

__global__ void scatter_kernel(const int* __restrict__ ei, int* __restrict__ cursor,
                               int* __restrict__ esrc) {
  int idx = blockIdx.x * 256 + threadIdx.x;
  if (idx >= ETOT) return;
  int s, d;
  if (idx < N_EDGES) { s = ei[idx]; d = ei[N_EDGES + idx]; }
  else { s = idx - N_EDGES; d = s; }
  int pos = atomicAdd(&cursor[d], 1);
  esrc[pos] = s;
}

// ---------------- MFMA GEMM NT with fp32 A (input projection, K=256) ----------
// A fp32 [M,K], converted to bf16 inline (same RTNE as f2bf pass — bit identical).
__global__ __launch_bounds__(256) void gemm_mfma_f32a(
    const float* __restrict__ A,           // [M,K] fp32 row-major
    const unsigned short* __restrict__ B,  // [Nc,K] bf16 row-major
    unsigned short* __restrict__ Cb,       // [M,Nc] bf16 out
    int M, int Nc, int K,
    const float* __restrict__ bias, int do_relu)
{
  int lane = threadIdx.x & 63;
  int wid  = threadIdx.x >> 6;
  int wm = wid >> 1, wn = wid & 1;
  int m0 = blockIdx.y * 128 + wm * 64;
  int n0 = blockIdx.x * 128 + wn * 64;
  int lr = lane & 15;
  int kg = lane >> 4;

  f32x4 acc[4][4];
  #pragma unroll
  for (int i = 0; i < 4; ++i)
    #pragma unroll
    for (int j = 0; j < 4; ++j)
      acc[i][j] = (f32x4){0.f, 0.f, 0.f, 0.f};

  size_t abase[4], bbase[4];
  #pragma unroll
  for (int i = 0; i < 4; ++i) {
    int ar = m0 + i * 16 + lr;
    if (ar >= M) ar = M - 1;
    abase[i] = (size_t)ar * K;
    bbase[i] = (size_t)(n0 + i * 16 + lr) * K;
  }

  int nk = K >> 5;
  float4 pa[4][2], na[4][2];
  short8 bfr[4], b2[4];
  #pragma unroll
  for (int i = 0; i < 4; ++i) {
    pa[i][0] = *(const float4*)&A[abase[i] + kg * 8];
    pa[i][1] = *(const float4*)&A[abase[i] + kg * 8 + 4];
    bfr[i] = *(const short8*)&B[bbase[i] + kg * 8];
  }
  for (int ks = 0; ks < nk; ++ks) {
    if (ks + 1 < nk) {
      int ko = (ks + 1) * 32 + kg * 8;
      #pragma unroll
      for (int i = 0; i < 4; ++i) {
        na[i][0] = *(const float4*)&A[abase[i] + ko];
        na[i][1] = *(const float4*)&A[abase[i] + ko + 4];
        b2[i] = *(const short8*)&B[bbase[i] + ko];
      }
    }
    short8 af[4];
    #pragma unroll
    for (int i = 0; i < 4; ++i) af[i] = pack8(pa[i][0], pa[i][1]);
    #pragma unroll
    for (int i = 0; i < 4; ++i)
      #pragma unroll
      for (int j = 0; j < 4; ++j)
        acc[i][j] = __builtin_amdgcn_mfma_f32_16x16x32_bf16(af[i], bfr[j], acc[i][j], 0, 0, 0);
    if (ks + 1 < nk) {
      #pragma unroll
      for (int i = 0; i < 4; ++i) {
        pa[i][0] = na[i][0]; pa[i][1] = na[i][1]; bfr[i] = b2[i];
      }
    }
  }

  float bz[4];
  #pragma unroll
  for (int j = 0; j < 4; ++j)
    bz[j] = bias ? bias[n0 + j * 16 + lr] : 0.f;
  #pragma unroll
  for (int i = 0; i < 4; ++i) {
    #pragma unroll
    for (int r = 0; r < 4; ++r) {
      int row = m0 + i * 16 + kg * 4 + r;
      if (row < M) {
        size_t rb = (size_t)row * Nc;
        #pragma unroll
        for (int j = 0; j < 4; ++j) {
          float v = acc[i][j][r] + bz[j];
          if (do_relu) v = fmaxf(v, 0.f);
          Cb[rb + n0 + j * 16 + lr] = f2bf(v);
        }
      }
    }
  }
}

// ---------------- K=128 specialized MFMA GEMM: all fragments prefetched ----------
__global__ __launch_bounds__(256) void gemm_mfma_k128(
    const unsigned short* __restrict__ A,  // [M,128] bf16
    const unsigned short* __restrict__ B,  // [Nc,128] bf16
    unsigned short* __restrict__ Cb,       // [M,Nc] bf16 out
    int M, int Nc)
{
  int lane = threadIdx.x & 63;
  int wid  = threadIdx.x >> 6;
  int wm = wid >> 1, wn = wid & 1;
  int m0 = blockIdx.y * 128 + wm * 64;
  int n0 = blockIdx.x * 128 + wn * 64;
  int lr = lane & 15;
  int kg = lane >> 4;

  const unsigned short* Ap[4];
  const unsigned short* Bp[4];
  #pragma unroll
  for (int i = 0; i < 4; ++i) {
    int ar = m0 + i * 16 + lr;
    if (ar >= M) ar = M - 1;
    Ap[i] = A + (size_t)ar * 128 + kg * 8;
    Bp[i] = B + (size_t)(n0 + i * 16 + lr) * 128 + kg * 8;
  }

  short8 a[4][4], b[4][4];
  #pragma unroll
  for (int ks = 0; ks < 4; ++ks)
    #pragma unroll
    for (int i = 0; i < 4; ++i) {
      a[ks][i] = *(const short8*)(Ap[i] + ks * 32);
      b[ks][i] = *(const short8*)(Bp[i] + ks * 32);
    }

  f32x4 acc[4][4];
  #pragma unroll
  for (int i = 0; i < 4; ++i)
    #pragma unroll
    for (int j = 0; j < 4; ++j)
      acc[i][j] = (f32x4){0.f, 0.f, 0.f, 0.f};

  #pragma unroll
  for (int ks = 0; ks < 4; ++ks)
    #pragma unroll
    for (int i = 0; i < 4; ++i)
      #pragma unroll
      for (int j = 0; j < 4; ++j)
        acc[i][j] = __builtin_amdgcn_mfma_f32_16x16x32_bf16(a[ks][i], b[ks][j], acc[i][j], 0, 0, 0);

  #pragma unroll
  for (int i = 0; i < 4; ++i) {
    #pragma unroll
    for (int r = 0; r < 4; ++r) {
      int row = m0 + i * 16 + kg * 4 + r;
      if (row < M) {
        size_t rb = (size_t)row * Nc;
        #pragma unroll
        for (int j = 0; j < 4; ++j)
          Cb[rb + n0 + j * 16 + lr] = f2bf(acc[i][j][r]);
      }
    }
  }
}

// ---------------- attention dot products (bf16 h): a_src/a_dst [N,4] ----------------
__global__ __launch_bounds__(256) void attn_dots(const unsigned short* __restrict__ HPh,
    const float* __restrict__ atts, const float* __restrict__ attd,
    float* __restrict__ a_s, float* __restrict__ a_d)
{
  int lane = threadIdx.x & 63;
  int n = blockIdx.x * 4 + (threadIdx.x >> 6);
  uint4 u = *(const uint4*)&HPh[(size_t)n * HPD + lane * 8];
  float p0, p1, p2, p3, p4, p5, p6, p7;
  bf2x(u.x, p0, p1); bf2x(u.y, p2, p3); bf2x(u.z, p4, p5); bf2x(u.w, p6, p7);
  const float4* wsv = (const float4*)&atts[lane * 8];
  float4 s0 = wsv[0], s1 = wsv[1];
  const float4* wdv = (const float4*)&attd[lane * 8];
  float4 d0 = wdv[0], d1 = wdv[1];
  float ps = p0*s0.x + p1*s0.y + p2*s0.z + p3*s0.w
           + p4*s1.x + p5*s1.y + p6*s1.z + p7*s1.w;
  float pd = p0*d0.x + p1*d0.y + p2*d0.z + p3*d0.w
           + p4*d1.x + p5*d1.y + p6*d1.z + p7*d1.w;
  #pragma unroll
  for (int m = 1; m <= 8; m <<= 1) {
    ps += __shfl_xor(ps, m);
    pd += __shfl_xor(pd, m);
  }
  if ((lane & 15) == 0) {
    int h = lane >> 4;
    a_s[n * NH + h] = ps;
    a_d[n * NH + h] = pd;
  }
}

// ---------------- per-dst softmax + weighted aggregation + head-mean ----------------
__global__ __launch_bounds__(256) void aggregate(const unsigned short* __restrict__ HPh,
    const float* __restrict__ a_s, const float* __restrict__ a_d,
    const int* __restrict__ offs, const int* __restrict__ esrc,
    const float* __restrict__ gbias, float* __restrict__ hout)
{
  int lane = threadIdx.x & 63;
  int n = blockIdx.x * 4 + (threadIdx.x >> 6);
  int start = offs[n], end = offs[n + 1];
  float4 ad4 = *(const float4*)&a_d[n * NH];
  int hsel = lane >> 4;
  int di = lane * 8;

  float4 m4 = make_float4(-1e30f, -1e30f, -1e30f, -1e30f);
  for (int j = start + lane; j < end; j += 64) {
    int s = esrc[j];
    float4 as4 = *(const float4*)&a_s[s * NH];
    m4.x = fmaxf(m4.x, lrelu(as4.x + ad4.x));
    m4.y = fmaxf(m4.y, lrelu(as4.y + ad4.y));
    m4.z = fmaxf(m4.z, lrelu(as4.z + ad4.z));
    m4.w = fmaxf(m4.w, lrelu(as4.w + ad4.w));
  }
  #pragma unroll
  for (int m = 1; m < 64; m <<= 1) {
    m4.x = fmaxf(m4.x, __shfl_xor(m4.x, m));
    m4.y = fmaxf(m4.y, __shfl_xor(m4.y, m));
    m4.z = fmaxf(m4.z, __shfl_xor(m4.z, m));
    m4.w = fmaxf(m4.w, __shfl_xor(m4.w, m));
  }
  float mh = (lane & 32) ? ((lane & 16) ? m4.w : m4.z) : ((lane & 16) ? m4.y : m4.x);
  float ad = (lane & 32) ? ((lane & 16) ? ad4.w : ad4.z) : ((lane & 16) ? ad4.y : ad4.x);

  float wacc = 0.f;
  float a0=0,a1=0,a2=0,a3=0,a4=0,a5=0,a6=0,a7=0;
  int sl = lane & 48;
  for (int base = start; base < end; base += 16) {
    int e = lane & 15;
    int j = base + e;
    float w = 0.f; int s = 0;
    if (j < end) {
      s = esrc[j];
      float a = a_s[s * NH + hsel];
      w = __expf(lrelu(a + ad) - mh);
    }
    wacc += w;
    int cnt = min(16, end - base);
    int t = 0;
    for (; t + 3 < cnt; t += 4) {
      int s0 = __shfl(s, sl | t);
      int s1 = __shfl(s, sl | (t + 1));
      int s2 = __shfl(s, sl | (t + 2));
      int s3 = __shfl(s, sl | (t + 3));
      float w0 = __shfl(w, sl | t);
      float w1 = __shfl(w, sl | (t + 1));
      float w2 = __shfl(w, sl | (t + 2));
      float w3 = __shfl(w, sl | (t + 3));
      uint4 u0 = *(const uint4*)&HPh[(size_t)s0 * HPD + di];
      uint4 u1 = *(const uint4*)&HPh[(size_t)s1 * HPD + di];
      uint4 u2 = *(const uint4*)&HPh[(size_t)s2 * HPD + di];
      uint4 u3 = *(const uint4*)&HPh[(size_t)s3 * HPD + di];
      float f0, f1, f2, f3, f4, f5, f6, f7;
      bf2x(u0.x, f0, f1); bf2x(u0.y, f2, f3); bf2x(u0.z, f4, f5); bf2x(u0.w, f6, f7);
      a0 = fmaf(w0, f0, a0); a1 = fmaf(w0, f1, a1); a2 = fmaf(w0, f2, a2); a3 = fmaf(w0, f3, a3);
      a4 = fmaf(w0, f4, a4); a5 = fmaf(w0, f5, a5); a6 = fmaf(w0, f6, a6); a7 = fmaf(w0, f7, a7);
      bf2x(u1.x, f0, f1); bf2x(u1.y, f2, f3); bf2x(u1.z, f4, f5); bf2x(u1.w, f6, f7);
      a0 = fmaf(w1, f0, a0); a1 = fmaf(w1, f1, a1); a2 = fmaf(w1, f2, a2); a3 = fmaf(w1, f3, a3);
      a4 = fmaf(w1, f4, a4); a5 = fmaf(w1, f5, a5); a6 = fmaf(w1, f6, a6); a7 = fmaf(w1, f7, a7);
      bf2x(u2.x, f0, f1); bf2x(u2.y, f2, f3); bf2x(u2.z, f4, f5); bf2x(u2.w, f6, f7);
      a0 = fmaf(w2, f0, a0); a1 = fmaf(w2, f1, a1); a2 = fmaf(w2, f2, a2); a3 = fmaf(w2, f3, a3);
      a4 = fmaf(w2, f4, a4); a5 = fmaf(w2, f5, a5); a6 = fmaf(w2, f6, a6); a7 = fmaf(w2, f7, a7);
      bf2x(u3.x, f0, f1); bf2x(u3.y, f2, f3); bf2x(u3.z, f4, f5); bf2x(u3.w, f6, f7);
      a0 = fmaf(w3, f0, a0); a1 = fmaf(w3, f1, a1); a2 = fmaf(w3, f2, a2); a3 = fmaf(w3, f3, a3);
      a4 = fmaf(w3, f4, a4); a5 = fmaf(w3, f5, a5); a6 = fmaf(w3, f6, a6); a7 = fmaf(w3, f7, a7);
    }
    for (; t < cnt; ++t) {
      int sj = __shfl(s, sl | t);
      float wj = __shfl(w, sl | t);
      uint4 u = *(const uint4*)&HPh[(size_t)sj * HPD + di];
      float f0, f1, f2, f3, f4, f5, f6, f7;
      bf2x(u.x, f0, f1); bf2x(u.y, f2, f3); bf2x(u.z, f4, f5); bf2x(u.w, f6, f7);
      a0 = fmaf(wj, f0, a0); a1 = fmaf(wj, f1, a1); a2 = fmaf(wj, f2, a2); a3 = fmaf(wj, f3, a3);
      a4 = fmaf(wj, f4, a4); a5 = fmaf(wj, f5, a5); a6 = fmaf(wj, f6, a6); a7 = fmaf(wj, f7, a7);
    }
  }
  #pragma unroll
  for (int m = 1; m <= 8; m <<= 1) wacc += __shfl_xor(wacc, m);
  float inv = 1.f / (wacc + 1e-16f);
  float r0=a0*inv, r1=a1*inv, r2=a2*inv, r3=a3*inv;
  float r4=a4*inv, r5=a5*inv, r6=a6*inv, r7=a7*inv;
  #pragma unroll
  for (int m = 16; m <= 32; m <<= 1) {
    r0 += __shfl_xor(r0, m); r1 += __shfl_xor(r1, m);
    r2 += __shfl_xor(r2, m); r3 += __shfl_xor(r3, m);
    r4 += __shfl_xor(r4, m); r5 += __shfl_xor(r5, m);
    r6 += __shfl_xor(r6, m); r7 += __shfl_xor(r7, m);
  }
  if (lane < 16) {
    int dbase = lane * 8;
    const float4* gb = (const float4*)&gbias[dbase];
    float4 g0 = gb[0], g1 = gb[1];
    float4 o0 = make_float4(r0*0.25f + g0.x, r1*0.25f + g0.y, r2*0.25f + g0.z, r3*0.25f + g0.w);
    float4 o1 = make_float4(r4*0.25f + g1.x, r5*0.25f + g1.y, r6*0.25f + g1.z, r7*0.25f + g1.w);
    *(float4*)&hout[(size_t)n * DD + dbase] = o0;
    *(float4*)&hout[(size_t)n * DD + dbase + 4] = o1;
  }
}

// ---------------- batch norm: parallel stats with LDS pre-reduction ----------------
__global__ __launch_bounds__(256) void bn_stats(const float* __restrict__ h,
    float* __restrict__ bs, float* __restrict__ bq)
{
  __shared__ float rs[256], rq[256];
  int c = threadIdx.x & 127, ro = threadIdx.x >> 7;
  float s = 0.f, q = 0.f;
  for (int r = blockIdx.x * 2 + ro; r < N_NODES; r += 1024) {   // grid = 512
    float v = h[(size_t)r * DD + c];
    s += v; q = fmaf(v, v, q);
  }
  rs[threadIdx.x] = s; rq[threadIdx.x] = q;
  __syncthreads();
  if (threadIdx.x < 128) {
    atomicAdd(&bs[c], rs[c] + rs[c + 128]);
    atomicAdd(&bq[c], rq[c] + rq[c + 128]);
  }
}

__global__ __launch_bounds__(256) void bn_apply(const float* __restrict__ h,
    const float* __restrict__ bs, const float* __restrict__ bq,
    const float* __restrict__ g, const float* __restrict__ b,
    unsigned short* __restrict__ hbf)
{
  const float invN = 1.f / (float)N_NODES;
  int i4 = blockIdx.x * 256 + threadIdx.x;
  int c0 = (i4 * 4) & (DD - 1);
  float4 v = *(const float4*)&h[(size_t)i4 * 4];
  float4 s = *(const float4*)&bs[c0];
  float4 q = *(const float4*)&bq[c0];
  float4 gg = *(const float4*)&g[c0];
  float4 bb = *(const float4*)&b[c0];
  float mu, var;
  ushort4 o;
  mu = s.x * invN; var = q.x * invN - mu * mu;
  o.x = f2bf(fmaxf((v.x - mu) * rsqrtf(var + EPS_BN) * gg.x + bb.x, 0.f));
  mu = s.y * invN; var = q.y * invN - mu * mu;
  o.y = f2bf(fmaxf((v.y - mu) * rsqrtf(var + EPS_BN) * gg.y + bb.y, 0.f));
  mu = s.z * invN; var = q.z * invN - mu * mu;
  o.z = f2bf(fmaxf((v.z - mu) * rsqrtf(var + EPS_BN) * gg.z + bb.z, 0.f));
  mu = s.w * invN; var = q.w * invN - mu * mu;
  o.w = f2bf(fmaxf((v.w - mu) * rsqrtf(var + EPS_BN) * gg.w + bb.w, 0.f));
  *(ushort4*)&hbf[(size_t)i4 * 4] = o;
}

// ---------------- global mean pool: parallel partial sums ----------------
__global__ __launch_bounds__(256) void pool_partial(const unsigned short* __restrict__ hbf,
    const int* __restrict__ batch, float* __restrict__ psum)
{
  int g = blockIdx.x >> 3, sl = blockIdx.x & 7;
  int lo = 0, hi = N_NODES;
  while (lo < hi) { int mid = (lo + hi) >> 1; if (batch[mid] < g) lo = mid + 1; else hi = mid; }
  int start = lo;
  hi = N_NODES;
  while (lo < hi) { int mid = (lo + hi) >> 1; if (batch[mid] < g + 1) lo = mid + 1; else hi = mid; }
  int end = lo;
  int c = threadIdx.x & 127, ro = threadIdx.x >> 7;
  float s = 0.f;
  for (int r = start + sl * 2 + ro; r < end; r += 16) s += bf2f(hbf[(size_t)r * DD + c]);
  atomicAdd(&psum[g * DD + c], s);
}

// ---------------- MLP heads (divides pooled sums by count) ----------------
__global__ __launch_bounds__(64) void heads_kernel(const float* __restrict__ psum,
    const int* __restrict__ batch,
    const float* __restrict__ hw1, const float* __restrict__ hb1,
    const float* __restrict__ hw2, const float* __restrict__ hb2,
    float* __restrict__ out)
{
  int k = blockIdx.x >> 6;
  int g = blockIdx.x & 63;
  int o = threadIdx.x;
  int lo = 0, hi = N_NODES;
  while (lo < hi) { int mid = (lo + hi) >> 1; if (batch[mid] < g) lo = mid + 1; else hi = mid; }
  int start = lo;
  hi = N_NODES;
  while (lo < hi) { int mid = (lo + hi) >> 1; if (batch[mid] < g + 1) lo = mid + 1; else hi = mid; }
  float inv = 1.f / fmaxf((float)(lo - start), 1.f);
  const float4* p = (const float4*)&psum[g * DD];
  const float4* w = (const float4*)&hw1[((size_t)k * 64 + o) * DD];
  float dot = 0.f;
  #pragma unroll
  for (int d4 = 0; d4 < DD / 4; ++d4) {
    float4 pv = p[d4], wv = w[d4];
    dot += pv.x*wv.x + pv.y*wv.y + pv.z*wv.z + pv.w*wv.w;
  }
  float acc = fmaf(dot, inv, hb1[k * 64 + o]);
  float contrib = fmaxf(acc, 0.f) * hw2[k * 64 + o];
  #pragma unroll
  for (int m = 1; m < 64; m <<= 1) contrib += __shfl_xor(contrib, m);
  if (o == 0) out[g * 3 + k] = contrib + hb2[k];
}

extern "C" void kernel_launch(void* const* d_in, const int* in_sizes, int n_in,
                              void* d_out, int out_size, void* d_ws, size_t ws_size,
                              hipStream_t stream) {
  const float* x       = (const float*)d_in[0];
  const int*   ei      = (const int*)d_in[1];
  const int*   batch   = (const int*)d_in[2];
  const float* ip_w    = (const float*)d_in[3];
  const float* ip_b    = (const float*)d_in[4];
  const float* lin_w   = (const float*)d_in[5];
  const float* att_src = (const float*)d_in[6];
  const float* att_dst = (const float*)d_in[7];
  const float* gat_b   = (const float*)d_in[8];
  const float* bn_g    = (const float*)d_in[9];
  const float* bn_b    = (const float*)d_in[10];
  const float* hw1     = (const float*)d_in[11];
  const float* hb1     = (const float*)d_in[12];
  const float* hw2     = (const float*)d_in[13];
  const float* hb2     = (const float*)d_in[14];
  float* out = (float*)d_out;

  float* ws     = (float*)d_ws;
  float* hout   = ws;                              // [N,DD] fp32 (aggregate out)
  float* a_s    = hout + (size_t)N_NODES * DD;
  float* a_d    = a_s + (size_t)N_NODES * NH;
  float* bnsum  = a_d + (size_t)N_NODES * NH;      // NL*DD
  float* bnss   = bnsum + NL * DD;                 // NL*DD
  float* pooled = bnss + NL * DD;                  // NGRAPH*DD (psum)
  unsigned short* HPh   = (unsigned short*)(pooled + NGRAPH * DD);   // [N,HPD] bf16
  unsigned short* hbf   = HPh + (size_t)N_NODES * HPD;               // [N,DD] bf16
  unsigned short* ipw_b = hbf + (size_t)N_NODES * DD;                // DD*DIN bf16
  unsigned short* linw_b= ipw_b + DD * DIN;                          // NL*HPD*DD bf16
  int*   hist   = (int*)(linw_b + (size_t)NL * HPD * DD);
  int*   offs   = hist + (N_NODES + 4);
  int*   cursor = offs + (N_NODES + 4);
  int*   esrc   = cursor + (N_NODES + 4);
  int*   bsum   = esrc + ETOT + 4;

  hipMemsetAsync(hist, 0, N_NODES * sizeof(int), stream);
  hipMemsetAsync(bnsum, 0, 2 * NL * DD * sizeof(float), stream);
  hipMemsetAsync(pooled, 0, NGRAPH * DD * sizeof(float), stream);

  // weight conversions to bf16 (x converted inline in gemm_mfma_f32a)
  f2bf_kernel<<<(DD * DIN / 4 + 255) / 256, 256, 0, stream>>>(ip_w, ipw_b, DD * DIN / 4);
  f2bf_kernel<<<(NL * HPD * DD / 4 + 255) / 256, 256, 0, stream>>>(lin_w, linw_b, NL * HPD * DD / 4);

  hist_kernel<<<(ETOT + 255) / 256, 256, 0, stream>>>(ei, hist);
  scan_blk<<<SCAN_NB, 1024, 0, stream>>>(hist, offs, bsum);
  scan_top<<<1, 64, 0, stream>>>(bsum, offs);
  scan_fix<<<(N_NODES + 255) / 256, 256, 0, stream>>>(bsum, offs, cursor);
  scatter_kernel<<<(ETOT + 255) / 256, 256, 0, stream>>>(ei, cursor, esrc);

  const int MB = (N_NODES + 127) / 128;   // 157

  // input projection + relu -> hbf (bf16), A = fp32 x converted inline
  gemm_mfma_f32a<<<dim3(DD / 128, MB), 256, 0, stream>>>(
      x, ipw_b, hbf, N_NODES, DD, DIN, ip_b, 1);

  for (int l = 0; l < NL; ++l) {
    gemm_mfma_k128<<<dim3(HPD / 128, MB), 256, 0, stream>>>(
        hbf, linw_b + (size_t)l * HPD * DD, HPh, N_NODES, HPD);
    attn_dots<<<N_NODES / 4, 256, 0, stream>>>(
        HPh, att_src + (size_t)l * HPD, att_dst + (size_t)l * HPD, a_s, a_d);
    aggregate<<<N_NODES / 4, 256, 0, stream>>>(
        HPh, a_s, a_d, offs, esrc, gat_b + (size_t)l * DD, hout);
    bn_stats<<<512, 256, 0, stream>>>(hout, bnsum + l * DD, bnss + l * DD);
    bn_apply<<<(N_NODES * DD / 4) / 256, 256, 0, stream>>>(
        hout, bnsum + l * DD, bnss + l * DD, bn_g + (size_t)l * DD, bn_b + (size_t)l * DD, hbf);
  }

  pool_partial<<<NGRAPH * 8, 256, 0, stream>>>(hbf, batch, pooled);
  heads_kernel<<<NL * NGRAPH, 64, 0, stream>>>(pooled, batch, hw1, hb1, hw2, hb2, out);
}